// Round 10
// baseline (1648.120 us; speedup 1.0000x reference)
//
#include <hip/hip_runtime.h>
#include <stdint.h>

#define D 1024
#define N 200000
#define C 50
#define B 4096
#define CLS 4
#define KParts 16
#define CAP 4096
#define NSLAB 4
#define DS (D / NSLAB)              // 256 d-rows per slab
#define BC 128                      // columns per block
#define NBC ((N + BC - 1) / BC)     // 1563 column blocks
#define NB2 (2 * 782)               // 1564 reduce blocks (2 c-halves x 782)
#define NSLOT (NB2 * 4)             // 6256 wave range slots

typedef float v2f __attribute__((ext_vector_type(2)));

// ws float offsets
static const size_t OFF_U     = 0;                            // C*N uints (ordering keys)
static const size_t OFF_TESQ  = (size_t)C * N;                // N floats
static const size_t OFF_PART  = OFF_TESQ + N;                 // NSLAB*51*N floats
static const size_t OFF_GPART = OFF_PART + (size_t)NSLAB * 51 * N;  // KParts*2500
static const size_t OFF_WPART = OFF_GPART + KParts * 2500;    // KParts*200
static const size_t OFF_RANGE = OFF_WPART + KParts * 200;     // NSLOT*2 uints
static const size_t OFF_SUMS  = OFF_RANGE + 2 * NSLOT;        // C floats
static const size_t OFF_CNT   = OFF_SUMS + C;                 // 1 uint
static const size_t OFF_W8    = ((OFF_CNT + 1 + 3) / 4) * 4;  // D*8 floats, 16B-aligned

__device__ __forceinline__ unsigned mapf(float v) {
    unsigned u = __float_as_uint(v);
    return (u & 0x80000000u) ? ~u : (u | 0x80000000u);
}
__device__ __forceinline__ float unmapf(unsigned u) {
    unsigned b = (u & 0x80000000u) ? (u ^ 0x80000000u) : ~u;
    return __uint_as_float(b);
}
// ordering key: tesq - 2*dot (monotone with dist2; csq constant per concept)
__device__ __forceinline__ unsigned keyu(float dot, float tesq) {
    return mapf(fmaf(-2.0f, dot, tesq));
}

// ---------------- K3a: tiled split-K dots partials (+16 gram-partial blocks) ----------------
__global__ __launch_bounds__(256) void k3a_dots(
    const float* __restrict__ concept, const float* __restrict__ te,
    const float* __restrict__ hxw, float* __restrict__ ws)
{
    int t = threadIdx.x;

    if (blockIdx.x < KParts) {
        // ---- partial gram + partial wc over a 64-row d-slab ----
        __shared__ __align__(16) float ct[64 * 50];
        __shared__ float hs[4 * 64];
        int bid = blockIdx.x;
        int d0 = bid * 64;

        for (int i = t; i < 64 * 50; i += 256) ct[i] = concept[d0 * 50 + i];
        {
            int j = t >> 6, dd = t & 63;
            hs[t] = hxw[j * D + d0 + dd];
        }
        __syncthreads();

        float* gp = ws + OFF_GPART + (size_t)bid * 2500;
        for (int p = t; p < 2500; p += 256) {
            int i = p / 50, j = p - i * 50;
            float acc = 0.f;
            #pragma unroll 8
            for (int dd = 0; dd < 64; ++dd)
                acc = fmaf(ct[dd * 50 + i], ct[dd * 50 + j], acc);
            gp[p] = acc;
        }
        float* wp = ws + OFF_WPART + (size_t)bid * 200;
        if (t < 200) {
            int j = t / 50, c = t - j * 50;
            float acc = 0.f;
            #pragma unroll 8
            for (int dd = 0; dd < 64; ++dd)
                acc = fmaf(hs[j * 64 + dd], ct[dd * 50 + c], acc);
            wp[t] = acc;
        }
        return;
    }

    // ---- dots partial: block = (slab s) x (128 columns), te staged via LDS ----
    __shared__ float lds[16][BC];
    int bi = blockIdx.x - KParts;
    int s = bi / NBC, j = bi - s * NBC;
    int nbase = j * BC;
    int dbase = s * DS;

    int i = t & (BC - 1);        // column within block
    int h = t >> 7;              // concept half: 0 -> c 0..23,48 ; 1 -> c 24..47,49
    int bc = h * 24;
    int ncol = nbase + i;

    v2f acc[12];
    #pragma unroll
    for (int q = 0; q < 12; ++q) acc[q] = (v2f)(0.0f);
    float accx = 0.f, tesq = 0.f;

    for (int d0 = 0; d0 < DS; d0 += 16) {
        __syncthreads();
        #pragma unroll
        for (int e = t; e < 16 * BC; e += 256) {
            int r = e >> 7, ii = e & (BC - 1);
            int col = nbase + ii;
            lds[r][ii] = (col < N) ? te[(size_t)(dbase + d0 + r) * N + col] : 0.f;
        }
        __syncthreads();
        #pragma unroll
        for (int r = 0; r < 16; ++r) {
            float x = lds[r][i];
            if (h == 0) tesq = fmaf(x, x, tesq);      // wave-uniform branch
            const float* crow = concept + (size_t)(dbase + d0 + r) * 50;
            const v2f* cr2 = (const v2f*)(crow + bc); // bc even -> 8B aligned
            v2f xv; xv[0] = x; xv[1] = x;
            #pragma unroll
            for (int q = 0; q < 12; ++q)
                acc[q] = __builtin_elementwise_fma(xv, cr2[q], acc[q]);
            accx = fmaf(x, crow[48 + h], accx);
        }
    }

    if (ncol < N) {
        float* pb = ws + OFF_PART + (size_t)s * 51 * N + ncol;
        #pragma unroll
        for (int q = 0; q < 12; ++q) {
            pb[(size_t)(bc + 2 * q) * N]     = acc[q][0];
            pb[(size_t)(bc + 2 * q + 1) * N] = acc[q][1];
        }
        pb[(size_t)(48 + h) * N] = accx;
        if (h == 0) pb[(size_t)50 * N] = tesq;
    }
}

// ---------------- K3b: block 0 = solve (gram sum, metrics, GJ, W8); blocks 1.. = reduce+keys ---
__global__ __launch_bounds__(256) void k3b_reduce(
    const float* __restrict__ concept, const float* __restrict__ hxw,
    float* __restrict__ ws, float* __restrict__ out)
{
    int t = threadIdx.x;

    if (blockIdx.x == 0) {
        // ---- solve role (R8-proven body) ----
        __shared__ float gsh[2500];
        __shared__ float A[50 * 56];     // [G | wc^T | pad]
        __shared__ float colp[C];
        __shared__ float part[3][4];
        int lane = t & 63, wid = t >> 6;

        if (t == 0) ((unsigned*)(ws + OFF_CNT))[0] = 0u;   // k4 completion counter

        float s_all = 0.f, s_tr = 0.f, s_abs = 0.f;
        for (int p = t; p < 2500; p += 256) {
            float g = 0.f;
            #pragma unroll
            for (int b = 0; b < KParts; ++b)
                g += ws[OFF_GPART + (size_t)b * 2500 + p];
            gsh[p] = g;
            int i = p / 50, jj = p - i * 50;
            float e = (i == jj) ? 1.0f : 0.0f;
            s_all += g;
            if (i == jj) s_tr += g;
            s_abs += fabsf(g - e);
        }
        #pragma unroll
        for (int off = 32; off > 0; off >>= 1) {
            s_all += __shfl_down(s_all, off, 64);
            s_tr  += __shfl_down(s_tr,  off, 64);
            s_abs += __shfl_down(s_abs, off, 64);
        }
        if (lane == 0) { part[0][wid] = s_all; part[1][wid] = s_tr; part[2][wid] = s_abs; }
        __syncthreads();
        if (t == 0) {
            float a  = part[0][0] + part[0][1] + part[0][2] + part[0][3];
            float tr = part[1][0] + part[1][1] + part[1][2] + part[1][3];
            float ab = part[2][0] + part[2][1] + part[2][2] + part[2][3];
            out[32769] = (a - tr) / 2500.0f;   // L_sparse_2
            out[32770] = tr / 2500.0f;         // norm_metrics
            out[32771] = ab / 2500.0f;         // similarity_penalty
        }

        for (int p = t; p < 50 * 56; p += 256) {
            int r = p / 56, col = p - r * 56;
            float v = 0.f;
            if (col < 50) v = gsh[r * 50 + col];
            else if (col < 54) {
                float w = 0.f;
                #pragma unroll
                for (int b = 0; b < KParts; ++b)
                    w += ws[OFF_WPART + (size_t)b * 200 + (col - 50) * 50 + r];
                v = w;
            }
            A[p] = v;
        }
        __syncthreads();

        // pivotless Gauss-Jordan (G is SPD -> stable without pivoting)
        for (int pc = 0; pc < C; ++pc) {
            if (t < C) colp[t] = A[t * 56 + pc];
            __syncthreads();
            float pinv = 1.0f / colp[pc];
            if (t < 56) A[pc * 56 + t] *= pinv;
            __syncthreads();
            for (int p = t; p < 50 * 56; p += 256) {
                int r = p / 56, col = p - r * 56;
                if (r != pc) A[p] = fmaf(-colp[r], A[pc * 56 + col], A[p]);
            }
            __syncthreads();
        }

        // W8[d][0..3] = hxw[j][d]; W8[d][4..7] = sum_c concept[d][c] * A[c][50+j]
        for (int d = t; d < D; d += 256) {
            float wy0 = 0.f, wy1 = 0.f, wy2 = 0.f, wy3 = 0.f;
            for (int c = 0; c < C; ++c) {
                float cv = concept[d * 50 + c];
                wy0 = fmaf(cv, A[c * 56 + 50], wy0);
                wy1 = fmaf(cv, A[c * 56 + 51], wy1);
                wy2 = fmaf(cv, A[c * 56 + 52], wy2);
                wy3 = fmaf(cv, A[c * 56 + 53], wy3);
            }
            float4 lo, hi;
            lo.x = hxw[0 * D + d]; lo.y = hxw[1 * D + d];
            lo.z = hxw[2 * D + d]; lo.w = hxw[3 * D + d];
            hi.x = wy0; hi.y = wy1; hi.z = wy2; hi.w = wy3;
            *(float4*)(ws + OFF_W8 + (size_t)d * 8)     = lo;
            *(float4*)(ws + OFF_W8 + (size_t)d * 8 + 4) = hi;
        }
        return;
    }

    // ---- reduce role: sum slab partials -> keys + tesq + per-wave range ----
    int rb = blockIdx.x - 1;          // 0..NB2-1
    int h = rb & 1;                   // c-half: 0 -> c 0..24, 1 -> c 25..49
    int n = (rb >> 1) * 256 + t;

    unsigned umin = 0xFFFFFFFFu, umax = 0u;
    if (n < N) {
        float tesq = 0.f;
        #pragma unroll
        for (int s = 0; s < NSLAB; ++s)
            tesq += ws[OFF_PART + ((size_t)s * 51 + 50) * N + n];
        if (h == 0) ws[OFF_TESQ + n] = tesq;

        unsigned* uws = (unsigned*)ws;
        #pragma unroll
        for (int cc = 0; cc < 25; ++cc) {
            int c = h * 25 + cc;
            float dot = 0.f;
            #pragma unroll
            for (int s = 0; s < NSLAB; ++s)
                dot += ws[OFF_PART + ((size_t)s * 51 + c) * N + n];
            unsigned u = keyu(dot, tesq);
            uws[(size_t)c * N + n] = u;
            umin = min(umin, u);
            umax = max(umax, u);
        }
    }
    #pragma unroll
    for (int off = 32; off > 0; off >>= 1) {
        umin = min(umin, (unsigned)__shfl_down((int)umin, off, 64));
        umax = max(umax, (unsigned)__shfl_down((int)umax, off, 64));
    }
    if ((t & 63) == 0) {
        int gw = rb * 4 + (t >> 6);
        ((unsigned*)(ws + OFF_RANGE))[2 * gw]     = umin;
        ((unsigned*)(ws + OFF_RANGE))[2 * gw + 1] = umax;
    }
}

// ---------------- Kpred: [orig_pred | y_pred] = X @ W8 + bias -----------------
__global__ __launch_bounds__(256) void kpred(
    const float* __restrict__ X, const float* __restrict__ hxb,
    const float* __restrict__ ws, float* __restrict__ out)
{
    int t = threadIdx.x;
    int lane = t & 63, w = t >> 6;
    int r = blockIdx.x * 4 + w;
    const float* xr = X + (size_t)r * D;
    const float* w8 = ws + OFF_W8;

    float acc[8];
    #pragma unroll
    for (int j = 0; j < 8; ++j) acc[j] = 0.f;
    #pragma unroll
    for (int i = 0; i < 16; ++i) {
        int d = i * 64 + lane;
        float x = xr[d];
        float4 lo = *(const float4*)(w8 + (size_t)d * 8);
        float4 hi = *(const float4*)(w8 + (size_t)d * 8 + 4);
        acc[0] = fmaf(x, lo.x, acc[0]);
        acc[1] = fmaf(x, lo.y, acc[1]);
        acc[2] = fmaf(x, lo.z, acc[2]);
        acc[3] = fmaf(x, lo.w, acc[3]);
        acc[4] = fmaf(x, hi.x, acc[4]);
        acc[5] = fmaf(x, hi.y, acc[5]);
        acc[6] = fmaf(x, hi.z, acc[6]);
        acc[7] = fmaf(x, hi.w, acc[7]);
    }
    #pragma unroll
    for (int j = 0; j < 8; ++j) {
        float v = acc[j];
        #pragma unroll
        for (int off = 32; off > 0; off >>= 1) v += __shfl_down(v, off, 64);
        if (lane == 0) {
            float b = hxb[j & 3];
            if (j < 4) out[(size_t)r * CLS + j] = v + b;
            else       out[16384 + (size_t)r * CLS + (j - 4)] = v + b;
        }
    }
}

// ---------------- K4: GR preamble + top-k from u keys + fused L_sparse_1 ------
__global__ __launch_bounds__(1024) void k4_select(
    const float* __restrict__ ws, float* __restrict__ wsw,
    float* __restrict__ out, const int* __restrict__ topk)
{
    int c = blockIdx.x, t = threadIdx.x;
    int lane = t & 63, wid = t >> 6;
    const unsigned* uarr = (const unsigned*)ws + (size_t)c * N;
    const float* tesq = ws + OFF_TESQ;

    __shared__ unsigned hist[4096];
    __shared__ unsigned wsum[16], woff[16];
    __shared__ unsigned wmn[16], wmx[16];
    __shared__ unsigned sh_ulo, sh_uhi;
    __shared__ unsigned sh_bin; __shared__ int sh_rem;
    __shared__ int cnt;
    __shared__ unsigned cand_u[CAP];
    __shared__ int      cand_i[CAP];
    __shared__ float fred[16];

    // ---- preamble: global key range from wave slots (redundant per block, exact) ----
    {
        const unsigned* rg = (const unsigned*)(ws + OFF_RANGE);
        unsigned mn = 0xFFFFFFFFu, mx = 0u;
        for (int i = t; i < NSLOT; i += 1024) {
            mn = min(mn, rg[2 * i]);
            mx = max(mx, rg[2 * i + 1]);
        }
        #pragma unroll
        for (int off = 32; off > 0; off >>= 1) {
            mn = min(mn, (unsigned)__shfl_down((int)mn, off, 64));
            mx = max(mx, (unsigned)__shfl_down((int)mx, off, 64));
        }
        if (lane == 0) { wmn[wid] = mn; wmx[wid] = mx; }
        __syncthreads();
        if (t == 0) {
            unsigned m0 = 0xFFFFFFFFu, m1 = 0u;
            for (int w = 0; w < 16; ++w) { m0 = min(m0, wmn[w]); m1 = max(m1, wmx[w]); }
            sh_ulo = m0; sh_uhi = m1;
        }
        __syncthreads();
    }
    unsigned ubase = sh_ulo;
    unsigned ulo = sh_ulo, uhi = sh_uhi;
    int rem = *topk;
    unsigned long long width = (unsigned long long)(uhi - ulo) + 1ull;

    // ---- pass 1: histogram over 4096 linear bins of the global range ----
    for (int i = t; i < 4096; i += 1024) hist[i] = 0u;
    __syncthreads();
    for (int n = t; n < N; n += 1024) {
        unsigned u = uarr[n];
        unsigned bin = (unsigned)(((unsigned long long)(u - ubase) * 4096ull) / width);
        atomicAdd(&hist[bin], 1u);
    }
    __syncthreads();
    {
        unsigned b0 = (unsigned)t * 4u;
        unsigned h0 = hist[b0], h1 = hist[b0 + 1], h2 = hist[b0 + 2], h3 = hist[b0 + 3];
        unsigned s4 = h0 + h1 + h2 + h3;
        unsigned x = s4;
        #pragma unroll
        for (int off = 1; off < 64; off <<= 1) {
            unsigned y = (unsigned)__shfl_up((int)x, off, 64);
            if (lane >= off) x += y;
        }
        if (lane == 63) wsum[wid] = x;
        __syncthreads();
        if (t == 0) {
            unsigned run = 0;
            for (int w = 0; w < 16; ++w) { woff[w] = run; run += wsum[w]; }
        }
        __syncthreads();
        unsigned cumBefore = woff[wid] + x - s4;
        unsigned remu = (unsigned)rem;
        if (cumBefore < remu && remu <= cumBefore + s4) {
            unsigned cum = cumBefore, bin = b0, r2 = 1;
            unsigned hh[4] = {h0, h1, h2, h3};
            #pragma unroll
            for (int j = 0; j < 4; ++j) {
                if (cum + hh[j] >= remu) { bin = b0 + j; r2 = remu - cum; break; }
                cum += hh[j];
            }
            sh_bin = bin; sh_rem = (int)r2;
        }
        __syncthreads();
        unsigned b = sh_bin;
        rem = sh_rem;
        ulo = ubase + (unsigned)(((unsigned long long)b * width + 4095ull) / 4096ull);
        uhi = ubase + (unsigned)((((unsigned long long)(b + 1) * width + 4095ull) / 4096ull) - 1ull);
        __syncthreads();
    }

    // ---- final: sum recovered dots below cutoff bin; collect cutoff-bin candidates ----
    if (t == 0) cnt = 0;
    __syncthreads();
    float lsum = 0.f;
    for (int n = t; n < N; n += 1024) {
        unsigned u = uarr[n];
        if (u < ulo) {
            lsum += 0.5f * (tesq[n] - unmapf(u));   // dot = (tesq - key)/2
        } else if (u <= uhi) {
            int s = atomicAdd(&cnt, 1);
            if (s < CAP) { cand_u[s] = u; cand_i[s] = n; }
        }
    }
    __syncthreads();
    int cc = cnt < CAP ? cnt : CAP;
    for (int ci = t; ci < cc; ci += 1024) {
        unsigned ui = cand_u[ci]; int ii = cand_i[ci];
        int rank = 0;
        for (int j = 0; j < cc; ++j) {
            unsigned uj = cand_u[j];
            rank += (uj < ui || (uj == ui && cand_i[j] < ii)) ? 1 : 0;
        }
        if (rank < rem) lsum += 0.5f * (tesq[ii] - unmapf(ui));
    }
    #pragma unroll
    for (int off = 32; off > 0; off >>= 1) lsum += __shfl_down(lsum, off, 64);
    if (lane == 0) fred[wid] = lsum;
    __syncthreads();
    if (t == 0) {
        float tot = 0.f;
        for (int w = 0; w < 16; ++w) tot += fred[w];
        wsw[OFF_SUMS + c] = tot;
        __threadfence();
        unsigned done = atomicAdd((unsigned*)(wsw + OFF_CNT), 1u);
        if (done == C - 1) {
            float s = 0.f;
            for (int i = 0; i < C; ++i) s += atomicAdd(&wsw[OFF_SUMS + i], 0.0f);
            out[32768] = s / (float)((*topk) * C);
        }
    }
}

extern "C" void kernel_launch(void* const* d_in, const int* in_sizes, int n_in,
                              void* d_out, int out_size, void* d_ws, size_t ws_size,
                              hipStream_t stream) {
    (void)in_sizes; (void)n_in; (void)out_size; (void)ws_size;
    const float* concept = (const float*)d_in[0];
    const float* te      = (const float*)d_in[1];
    const float* X       = (const float*)d_in[2];
    const float* hxw     = (const float*)d_in[3];
    const float* hxb     = (const float*)d_in[4];
    const int*   topk    = (const int*)d_in[5];
    float* out = (float*)d_out;
    float* ws  = (float*)d_ws;

    k3a_dots<<<dim3(KParts + NSLAB * NBC), dim3(256), 0, stream>>>(concept, te, hxw, ws);
    k3b_reduce<<<dim3(1 + NB2), dim3(256), 0, stream>>>(concept, hxw, ws, out);
    kpred<<<dim3(B / 4), dim3(256), 0, stream>>>(X, hxb, ws, out);
    k4_select<<<dim3(C), dim3(1024), 0, stream>>>(ws, ws, out, topk);
}

// Round 11
// 995.421 us; speedup vs baseline: 1.6557x; 1.6557x over previous
//
#include <hip/hip_runtime.h>
#include <stdint.h>

#define D 1024
#define N 200000
#define C 50
#define B 4096
#define CLS 4
#define KParts 16
#define CAP 4096
#define NSLAB 2
#define DS (D / NSLAB)              // 512 d-rows per slab
#define NBC 391                     // ceil(200000 / 512) column blocks (512 cols each)
#define RB 782                      // ceil(N/256) reduce column-chunks
#define NB2 (2 * RB)                // reduce blocks (2 c-halves)
#define NSLOT (NB2 * 4)             // 6256 wave range slots

typedef float v2f __attribute__((ext_vector_type(2)));

// ws float offsets
static const size_t OFF_U     = 0;                            // C*N uints (ordering keys)
static const size_t OFF_TESQ  = (size_t)C * N;                // N floats
static const size_t OFF_PART  = OFF_TESQ + N;                 // NSLAB*51*N floats
static const size_t OFF_GPART = OFF_PART + (size_t)NSLAB * 51 * N;  // KParts*2500
static const size_t OFF_WPART = OFF_GPART + KParts * 2500;    // KParts*200
static const size_t OFF_RANGE = OFF_WPART + KParts * 200;     // NSLOT*2 uints
static const size_t OFF_SUMS  = OFF_RANGE + 2 * NSLOT;        // C floats
static const size_t OFF_CNT   = OFF_SUMS + C;                 // 1 uint
static const size_t OFF_W8    = ((OFF_CNT + 1 + 3) / 4) * 4;  // D*8 floats, 16B-aligned

__device__ __forceinline__ unsigned mapf(float v) {
    unsigned u = __float_as_uint(v);
    return (u & 0x80000000u) ? ~u : (u | 0x80000000u);
}
__device__ __forceinline__ float unmapf(unsigned u) {
    unsigned b = (u & 0x80000000u) ? (u ^ 0x80000000u) : ~u;
    return __uint_as_float(b);
}
// ordering key: tesq - 2*dot (monotone with dist2; csq constant per concept)
__device__ __forceinline__ unsigned keyu(float dot, float tesq) {
    return mapf(fmaf(-2.0f, dot, tesq));
}

// ---------------- K3a: dots partials — 2 cols/thread, LDS-staged concept, split-D x2 ----------
__global__ __launch_bounds__(256, 3) void k3a_dots(
    const float* __restrict__ concept, const float* __restrict__ te,
    const float* __restrict__ hxw, float* __restrict__ ws)
{
    int t = threadIdx.x;

    if (blockIdx.x < KParts) {
        // ---- partial gram + partial wc over a 64-row d-slab ----
        __shared__ __align__(16) float ct[64 * 50];
        __shared__ float hs[4 * 64];
        int bid = blockIdx.x;
        int d0 = bid * 64;

        for (int i = t; i < 64 * 50; i += 256) ct[i] = concept[d0 * 50 + i];
        {
            int j = t >> 6, dd = t & 63;
            hs[t] = hxw[j * D + d0 + dd];
        }
        __syncthreads();

        float* gp = ws + OFF_GPART + (size_t)bid * 2500;
        for (int p = t; p < 2500; p += 256) {
            int i = p / 50, j = p - i * 50;
            float acc = 0.f;
            #pragma unroll 8
            for (int dd = 0; dd < 64; ++dd)
                acc = fmaf(ct[dd * 50 + i], ct[dd * 50 + j], acc);
            gp[p] = acc;
        }
        float* wp = ws + OFF_WPART + (size_t)bid * 200;
        if (t < 200) {
            int j = t / 50, c = t - j * 50;
            float acc = 0.f;
            #pragma unroll 8
            for (int dd = 0; dd < 64; ++dd)
                acc = fmaf(hs[j * 64 + dd], ct[dd * 50 + c], acc);
            wp[t] = acc;
        }
        return;
    }

    // ---- dots partial ----
    __shared__ float cs[64 * 50];    // concept tile: 64 rows x 50 (12.8 KB)
    int bi = blockIdx.x - KParts;    // 0..2*NBC-1
    int s = bi / NBC, j = bi - s * NBC;
    int dbase = s * DS;
    int n0 = j * 512 + 2 * t;        // this thread's column pair
    bool active = (n0 < N);          // N even -> pair fully valid when n0 < N
    int nc = active ? n0 : 0;        // safe address for inactive threads

    v2f acc[50];
    #pragma unroll
    for (int c = 0; c < 50; ++c) acc[c] = (v2f)(0.0f);
    v2f tesq = (v2f)(0.0f);

    for (int d0 = 0; d0 < DS; d0 += 64) {
        __syncthreads();
        for (int e = t; e < 64 * 50; e += 256)
            cs[e] = concept[(size_t)(dbase + d0) * 50 + e];
        __syncthreads();

        #pragma unroll 1
        for (int r8 = 0; r8 < 64; r8 += 8) {
            v2f x[8];
            #pragma unroll
            for (int u = 0; u < 8; ++u)
                x[u] = *(const v2f*)(te + (size_t)(dbase + d0 + r8 + u) * N + nc);
            #pragma unroll
            for (int u = 0; u < 8; ++u) {
                tesq = __builtin_elementwise_fma(x[u], x[u], tesq);
                const v2f* cr = (const v2f*)(cs + (r8 + u) * 50);
                #pragma unroll
                for (int q = 0; q < 25; ++q) {
                    v2f cp = cr[q];                    // broadcast ds_read_b64
                    v2f c0; c0[0] = cp[0]; c0[1] = cp[0];
                    v2f c1; c1[0] = cp[1]; c1[1] = cp[1];
                    acc[2 * q]     = __builtin_elementwise_fma(x[u], c0, acc[2 * q]);
                    acc[2 * q + 1] = __builtin_elementwise_fma(x[u], c1, acc[2 * q + 1]);
                }
            }
        }
    }

    if (active) {
        float* pb = ws + OFF_PART + (size_t)s * 51 * N;
        #pragma unroll
        for (int c = 0; c < 50; ++c)
            *(v2f*)(pb + (size_t)c * N + n0) = acc[c];
        *(v2f*)(pb + (size_t)50 * N + n0) = tesq;
    }
}

// ---------------- K3b: block 0 = solve (gram sum, metrics, GJ, W8); blocks 1.. = reduce+keys ---
__global__ __launch_bounds__(256) void k3b_reduce(
    const float* __restrict__ concept, const float* __restrict__ hxw,
    float* __restrict__ ws, float* __restrict__ out)
{
    int t = threadIdx.x;

    if (blockIdx.x == 0) {
        // ---- solve role ----
        __shared__ float gsh[2500];
        __shared__ float A[50 * 56];     // [G | wc^T | pad]
        __shared__ float colp[C];
        __shared__ float part[3][4];
        int lane = t & 63, wid = t >> 6;

        if (t == 0) ((unsigned*)(ws + OFF_CNT))[0] = 0u;   // k4 completion counter

        float s_all = 0.f, s_tr = 0.f, s_abs = 0.f;
        for (int p = t; p < 2500; p += 256) {
            float g = 0.f;
            #pragma unroll
            for (int b = 0; b < KParts; ++b)
                g += ws[OFF_GPART + (size_t)b * 2500 + p];
            gsh[p] = g;
            int i = p / 50, jj = p - i * 50;
            float e = (i == jj) ? 1.0f : 0.0f;
            s_all += g;
            if (i == jj) s_tr += g;
            s_abs += fabsf(g - e);
        }
        #pragma unroll
        for (int off = 32; off > 0; off >>= 1) {
            s_all += __shfl_down(s_all, off, 64);
            s_tr  += __shfl_down(s_tr,  off, 64);
            s_abs += __shfl_down(s_abs, off, 64);
        }
        if (lane == 0) { part[0][wid] = s_all; part[1][wid] = s_tr; part[2][wid] = s_abs; }
        __syncthreads();
        if (t == 0) {
            float a  = part[0][0] + part[0][1] + part[0][2] + part[0][3];
            float tr = part[1][0] + part[1][1] + part[1][2] + part[1][3];
            float ab = part[2][0] + part[2][1] + part[2][2] + part[2][3];
            out[32769] = (a - tr) / 2500.0f;   // L_sparse_2
            out[32770] = tr / 2500.0f;         // norm_metrics
            out[32771] = ab / 2500.0f;         // similarity_penalty
        }

        for (int p = t; p < 50 * 56; p += 256) {
            int r = p / 56, col = p - r * 56;
            float v = 0.f;
            if (col < 50) v = gsh[r * 50 + col];
            else if (col < 54) {
                float w = 0.f;
                #pragma unroll
                for (int b = 0; b < KParts; ++b)
                    w += ws[OFF_WPART + (size_t)b * 200 + (col - 50) * 50 + r];
                v = w;
            }
            A[p] = v;
        }
        __syncthreads();

        // pivotless Gauss-Jordan (G is SPD -> stable without pivoting)
        for (int pc = 0; pc < C; ++pc) {
            if (t < C) colp[t] = A[t * 56 + pc];
            __syncthreads();
            float pinv = 1.0f / colp[pc];
            if (t < 56) A[pc * 56 + t] *= pinv;
            __syncthreads();
            for (int p = t; p < 50 * 56; p += 256) {
                int r = p / 56, col = p - r * 56;
                if (r != pc) A[p] = fmaf(-colp[r], A[pc * 56 + col], A[p]);
            }
            __syncthreads();
        }

        // W8[d][0..3] = hxw[j][d]; W8[d][4..7] = sum_c concept[d][c] * A[c][50+j]
        for (int d = t; d < D; d += 256) {
            float wy0 = 0.f, wy1 = 0.f, wy2 = 0.f, wy3 = 0.f;
            for (int c = 0; c < C; ++c) {
                float cv = concept[d * 50 + c];
                wy0 = fmaf(cv, A[c * 56 + 50], wy0);
                wy1 = fmaf(cv, A[c * 56 + 51], wy1);
                wy2 = fmaf(cv, A[c * 56 + 52], wy2);
                wy3 = fmaf(cv, A[c * 56 + 53], wy3);
            }
            float4 lo, hi;
            lo.x = hxw[0 * D + d]; lo.y = hxw[1 * D + d];
            lo.z = hxw[2 * D + d]; lo.w = hxw[3 * D + d];
            hi.x = wy0; hi.y = wy1; hi.z = wy2; hi.w = wy3;
            *(float4*)(ws + OFF_W8 + (size_t)d * 8)     = lo;
            *(float4*)(ws + OFF_W8 + (size_t)d * 8 + 4) = hi;
        }
        return;
    }

    // ---- reduce role: sum slab partials -> keys + tesq + per-wave range ----
    int rb = blockIdx.x - 1;          // 0..NB2-1
    int h = rb & 1;                   // c-half: 0 -> c 0..24, 1 -> c 25..49
    int n = (rb >> 1) * 256 + t;

    unsigned umin = 0xFFFFFFFFu, umax = 0u;
    if (n < N) {
        float tesq = ws[OFF_PART + (size_t)50 * N + n]
                   + ws[OFF_PART + ((size_t)51 + 50) * N + n];
        if (h == 0) ws[OFF_TESQ + n] = tesq;

        unsigned* uws = (unsigned*)ws;
        #pragma unroll
        for (int cc = 0; cc < 25; ++cc) {
            int c = h * 25 + cc;
            float dot = ws[OFF_PART + (size_t)c * N + n]
                      + ws[OFF_PART + ((size_t)51 + c) * N + n];
            unsigned u = keyu(dot, tesq);
            uws[(size_t)c * N + n] = u;
            umin = min(umin, u);
            umax = max(umax, u);
        }
    }
    #pragma unroll
    for (int off = 32; off > 0; off >>= 1) {
        umin = min(umin, (unsigned)__shfl_down((int)umin, off, 64));
        umax = max(umax, (unsigned)__shfl_down((int)umax, off, 64));
    }
    if ((t & 63) == 0) {
        int gw = rb * 4 + (t >> 6);
        ((unsigned*)(ws + OFF_RANGE))[2 * gw]     = umin;
        ((unsigned*)(ws + OFF_RANGE))[2 * gw + 1] = umax;
    }
}

// ---------------- Kpred: [orig_pred | y_pred] = X @ W8 + bias -----------------
__global__ __launch_bounds__(256) void kpred(
    const float* __restrict__ X, const float* __restrict__ hxb,
    const float* __restrict__ ws, float* __restrict__ out)
{
    int t = threadIdx.x;
    int lane = t & 63, w = t >> 6;
    int r = blockIdx.x * 4 + w;
    const float* xr = X + (size_t)r * D;
    const float* w8 = ws + OFF_W8;

    float acc[8];
    #pragma unroll
    for (int j = 0; j < 8; ++j) acc[j] = 0.f;
    #pragma unroll
    for (int i = 0; i < 16; ++i) {
        int d = i * 64 + lane;
        float x = xr[d];
        float4 lo = *(const float4*)(w8 + (size_t)d * 8);
        float4 hi = *(const float4*)(w8 + (size_t)d * 8 + 4);
        acc[0] = fmaf(x, lo.x, acc[0]);
        acc[1] = fmaf(x, lo.y, acc[1]);
        acc[2] = fmaf(x, lo.z, acc[2]);
        acc[3] = fmaf(x, lo.w, acc[3]);
        acc[4] = fmaf(x, hi.x, acc[4]);
        acc[5] = fmaf(x, hi.y, acc[5]);
        acc[6] = fmaf(x, hi.z, acc[6]);
        acc[7] = fmaf(x, hi.w, acc[7]);
    }
    #pragma unroll
    for (int j = 0; j < 8; ++j) {
        float v = acc[j];
        #pragma unroll
        for (int off = 32; off > 0; off >>= 1) v += __shfl_down(v, off, 64);
        if (lane == 0) {
            float b = hxb[j & 3];
            if (j < 4) out[(size_t)r * CLS + j] = v + b;
            else       out[16384 + (size_t)r * CLS + (j - 4)] = v + b;
        }
    }
}

// ---------------- K4: GR preamble + top-k from u keys + fused L_sparse_1 ------
__global__ __launch_bounds__(1024) void k4_select(
    const float* __restrict__ ws, float* __restrict__ wsw,
    float* __restrict__ out, const int* __restrict__ topk)
{
    int c = blockIdx.x, t = threadIdx.x;
    int lane = t & 63, wid = t >> 6;
    const unsigned* uarr = (const unsigned*)ws + (size_t)c * N;
    const float* tesq = ws + OFF_TESQ;

    __shared__ unsigned hist[4096];
    __shared__ unsigned wsum[16], woff[16];
    __shared__ unsigned wmn[16], wmx[16];
    __shared__ unsigned sh_ulo, sh_uhi;
    __shared__ unsigned sh_bin; __shared__ int sh_rem;
    __shared__ int cnt;
    __shared__ unsigned cand_u[CAP];
    __shared__ int      cand_i[CAP];
    __shared__ float fred[16];

    // ---- preamble: global key range from wave slots (redundant per block, exact) ----
    {
        const unsigned* rg = (const unsigned*)(ws + OFF_RANGE);
        unsigned mn = 0xFFFFFFFFu, mx = 0u;
        for (int i = t; i < NSLOT; i += 1024) {
            mn = min(mn, rg[2 * i]);
            mx = max(mx, rg[2 * i + 1]);
        }
        #pragma unroll
        for (int off = 32; off > 0; off >>= 1) {
            mn = min(mn, (unsigned)__shfl_down((int)mn, off, 64));
            mx = max(mx, (unsigned)__shfl_down((int)mx, off, 64));
        }
        if (lane == 0) { wmn[wid] = mn; wmx[wid] = mx; }
        __syncthreads();
        if (t == 0) {
            unsigned m0 = 0xFFFFFFFFu, m1 = 0u;
            for (int w = 0; w < 16; ++w) { m0 = min(m0, wmn[w]); m1 = max(m1, wmx[w]); }
            sh_ulo = m0; sh_uhi = m1;
        }
        __syncthreads();
    }
    unsigned ubase = sh_ulo;
    unsigned ulo = sh_ulo, uhi = sh_uhi;
    int rem = *topk;
    unsigned long long width = (unsigned long long)(uhi - ulo) + 1ull;

    // ---- pass 1: histogram over 4096 linear bins of the global range ----
    for (int i = t; i < 4096; i += 1024) hist[i] = 0u;
    __syncthreads();
    for (int n = t; n < N; n += 1024) {
        unsigned u = uarr[n];
        unsigned bin = (unsigned)(((unsigned long long)(u - ubase) * 4096ull) / width);
        atomicAdd(&hist[bin], 1u);
    }
    __syncthreads();
    {
        unsigned b0 = (unsigned)t * 4u;
        unsigned h0 = hist[b0], h1 = hist[b0 + 1], h2 = hist[b0 + 2], h3 = hist[b0 + 3];
        unsigned s4 = h0 + h1 + h2 + h3;
        unsigned x = s4;
        #pragma unroll
        for (int off = 1; off < 64; off <<= 1) {
            unsigned y = (unsigned)__shfl_up((int)x, off, 64);
            if (lane >= off) x += y;
        }
        if (lane == 63) wsum[wid] = x;
        __syncthreads();
        if (t == 0) {
            unsigned run = 0;
            for (int w = 0; w < 16; ++w) { woff[w] = run; run += wsum[w]; }
        }
        __syncthreads();
        unsigned cumBefore = woff[wid] + x - s4;
        unsigned remu = (unsigned)rem;
        if (cumBefore < remu && remu <= cumBefore + s4) {
            unsigned cum = cumBefore, bin = b0, r2 = 1;
            unsigned hh[4] = {h0, h1, h2, h3};
            #pragma unroll
            for (int j = 0; j < 4; ++j) {
                if (cum + hh[j] >= remu) { bin = b0 + j; r2 = remu - cum; break; }
                cum += hh[j];
            }
            sh_bin = bin; sh_rem = (int)r2;
        }
        __syncthreads();
        unsigned b = sh_bin;
        rem = sh_rem;
        ulo = ubase + (unsigned)(((unsigned long long)b * width + 4095ull) / 4096ull);
        uhi = ubase + (unsigned)((((unsigned long long)(b + 1) * width + 4095ull) / 4096ull) - 1ull);
        __syncthreads();
    }

    // ---- final: sum recovered dots below cutoff bin; collect cutoff-bin candidates ----
    if (t == 0) cnt = 0;
    __syncthreads();
    float lsum = 0.f;
    for (int n = t; n < N; n += 1024) {
        unsigned u = uarr[n];
        if (u < ulo) {
            lsum += 0.5f * (tesq[n] - unmapf(u));   // dot = (tesq - key)/2
        } else if (u <= uhi) {
            int s = atomicAdd(&cnt, 1);
            if (s < CAP) { cand_u[s] = u; cand_i[s] = n; }
        }
    }
    __syncthreads();
    int cc = cnt < CAP ? cnt : CAP;
    for (int ci = t; ci < cc; ci += 1024) {
        unsigned ui = cand_u[ci]; int ii = cand_i[ci];
        int rank = 0;
        for (int j = 0; j < cc; ++j) {
            unsigned uj = cand_u[j];
            rank += (uj < ui || (uj == ui && cand_i[j] < ii)) ? 1 : 0;
        }
        if (rank < rem) lsum += 0.5f * (tesq[ii] - unmapf(ui));
    }
    #pragma unroll
    for (int off = 32; off > 0; off >>= 1) lsum += __shfl_down(lsum, off, 64);
    if (lane == 0) fred[wid] = lsum;
    __syncthreads();
    if (t == 0) {
        float tot = 0.f;
        for (int w = 0; w < 16; ++w) tot += fred[w];
        wsw[OFF_SUMS + c] = tot;
        __threadfence();
        unsigned done = atomicAdd((unsigned*)(wsw + OFF_CNT), 1u);
        if (done == C - 1) {
            float s = 0.f;
            for (int i = 0; i < C; ++i) s += atomicAdd(&wsw[OFF_SUMS + i], 0.0f);
            out[32768] = s / (float)((*topk) * C);
        }
    }
}

extern "C" void kernel_launch(void* const* d_in, const int* in_sizes, int n_in,
                              void* d_out, int out_size, void* d_ws, size_t ws_size,
                              hipStream_t stream) {
    (void)in_sizes; (void)n_in; (void)out_size; (void)ws_size;
    const float* concept = (const float*)d_in[0];
    const float* te      = (const float*)d_in[1];
    const float* X       = (const float*)d_in[2];
    const float* hxw     = (const float*)d_in[3];
    const float* hxb     = (const float*)d_in[4];
    const int*   topk    = (const int*)d_in[5];
    float* out = (float*)d_out;
    float* ws  = (float*)d_ws;

    k3a_dots<<<dim3(KParts + NSLAB * NBC), dim3(256), 0, stream>>>(concept, te, hxw, ws);
    k3b_reduce<<<dim3(1 + NB2), dim3(256), 0, stream>>>(concept, hxw, ws, out);
    kpred<<<dim3(B / 4), dim3(256), 0, stream>>>(X, hxb, ws, out);
    k4_select<<<dim3(C), dim3(1024), 0, stream>>>(ws, ws, out, topk);
}

// Round 12
// 910.103 us; speedup vs baseline: 1.8109x; 1.0937x over previous
//
#include <hip/hip_runtime.h>
#include <stdint.h>

#define D 1024
#define N 200000
#define C 50
#define B 4096
#define CLS 4
#define KParts 16
#define CAP 4096
#define NSLAB 2
#define DS (D / NSLAB)              // 512 d-rows per slab
#define NBC 196                     // ceil(200000/1024) column blocks (1024 cols each)
#define RB 782                      // ceil(N/256) reduce column-chunks
#define NB2 (2 * RB)                // reduce blocks (2 c-halves)
#define NSLOT (NB2 * 4)             // wave range slots

typedef float v2f __attribute__((ext_vector_type(2)));

// ws float offsets
static const size_t OFF_U     = 0;                            // C*N uints (ordering keys)
static const size_t OFF_TESQ  = (size_t)C * N;                // N floats
static const size_t OFF_PART  = OFF_TESQ + N;                 // NSLAB*51*N floats
static const size_t OFF_GPART = OFF_PART + (size_t)NSLAB * 51 * N;  // KParts*2500
static const size_t OFF_WPART = OFF_GPART + KParts * 2500;    // KParts*200
static const size_t OFF_RANGE = OFF_WPART + KParts * 200;     // NSLOT*2 uints
static const size_t OFF_SUMS  = OFF_RANGE + 2 * NSLOT;        // C floats
static const size_t OFF_CNT   = OFF_SUMS + C;                 // 1 uint
static const size_t OFF_W8    = ((OFF_CNT + 1 + 3) / 4) * 4;  // D*8 floats, 16B-aligned

__device__ __forceinline__ unsigned mapf(float v) {
    unsigned u = __float_as_uint(v);
    return (u & 0x80000000u) ? ~u : (u | 0x80000000u);
}
__device__ __forceinline__ float unmapf(unsigned u) {
    unsigned b = (u & 0x80000000u) ? (u ^ 0x80000000u) : ~u;
    return __uint_as_float(b);
}
// ordering key: tesq - 2*dot (monotone with dist2; csq constant per concept)
__device__ __forceinline__ unsigned keyu(float dot, float tesq) {
    return mapf(fmaf(-2.0f, dot, tesq));
}

// ---------------- K3a: dots partials — 4 cols/thread (1KB/wave bursts), c-half, D-split x2 ----
__global__ __launch_bounds__(256, 3) void k3a_dots(
    const float* __restrict__ concept, const float* __restrict__ te,
    const float* __restrict__ hxw, float* __restrict__ ws)
{
    __shared__ __align__(16) float sbuf[3584];   // shared by both branches (14.3 KB)
    int t = threadIdx.x;

    if (blockIdx.x < KParts) {
        // ---- partial gram + partial wc over a 64-row d-slab ----
        float* ct = sbuf;            // [64*50]
        float* hs = sbuf + 3328;     // [256]
        int bid = blockIdx.x;
        int d0 = bid * 64;

        for (int i = t; i < 64 * 50; i += 256) ct[i] = concept[d0 * 50 + i];
        {
            int j = t >> 6, dd = t & 63;
            hs[t] = hxw[j * D + d0 + dd];
        }
        __syncthreads();

        float* gp = ws + OFF_GPART + (size_t)bid * 2500;
        for (int p = t; p < 2500; p += 256) {
            int i = p / 50, j = p - i * 50;
            float acc = 0.f;
            #pragma unroll 8
            for (int dd = 0; dd < 64; ++dd)
                acc = fmaf(ct[dd * 50 + i], ct[dd * 50 + j], acc);
            gp[p] = acc;
        }
        float* wp = ws + OFF_WPART + (size_t)bid * 200;
        if (t < 200) {
            int j = t / 50, c = t - j * 50;
            float acc = 0.f;
            #pragma unroll 8
            for (int dd = 0; dd < 64; ++dd)
                acc = fmaf(hs[j * 64 + dd], ct[dd * 50 + c], acc);
            wp[t] = acc;
        }
        return;
    }

    // ---- dots partial: block = (slab s) x (c-half h) x (1024 cols), 4 cols/thread ----
    // LDS concept tile layout: [64 rows][56]: half0 at cols 0..24, half1 at 28..52 (16B-aligned)
    int bi = blockIdx.x - KParts;            // 0 .. 2*2*NBC-1
    int s = bi / (2 * NBC);
    int rem = bi - s * (2 * NBC);
    int h = rem / NBC, j = rem - h * NBC;
    int dbase = s * DS;
    int n0 = j * 1024 + 4 * t;
    bool active = (n0 < N);                  // N%4==0 -> 4-col group fully valid
    int nc = active ? n0 : 0;

    v2f acc[25][2];
    #pragma unroll
    for (int c = 0; c < 25; ++c) { acc[c][0] = (v2f)(0.0f); acc[c][1] = (v2f)(0.0f); }
    v2f tqa = (v2f)(0.0f), tqb = (v2f)(0.0f);

    for (int d0 = 0; d0 < DS; d0 += 64) {
        __syncthreads();
        for (int e = t; e < 64 * 50; e += 256) {
            int r = e / 50, cc = e - r * 50;
            sbuf[r * 56 + (cc < 25 ? cc : cc + 3)] = concept[(size_t)(dbase + d0) * 50 + e];
        }
        __syncthreads();

        #pragma unroll 1
        for (int r4 = 0; r4 < 64; r4 += 4) {
            float4 x[4];
            #pragma unroll
            for (int u = 0; u < 4; ++u)
                x[u] = *(const float4*)(te + (size_t)(dbase + d0 + r4 + u) * N + nc);
            #pragma unroll
            for (int u = 0; u < 4; ++u) {
                v2f xa; xa[0] = x[u].x; xa[1] = x[u].y;
                v2f xb; xb[0] = x[u].z; xb[1] = x[u].w;
                if (h == 0) {                         // wave-uniform branch
                    tqa = __builtin_elementwise_fma(xa, xa, tqa);
                    tqb = __builtin_elementwise_fma(xb, xb, tqb);
                }
                const float* csrow = sbuf + (r4 + u) * 56 + h * 28;
                const float4* cr4 = (const float4*)csrow;   // 16B-aligned
                float cv[25];
                #pragma unroll
                for (int q = 0; q < 6; ++q) {
                    float4 c4 = cr4[q];
                    cv[4 * q + 0] = c4.x; cv[4 * q + 1] = c4.y;
                    cv[4 * q + 2] = c4.z; cv[4 * q + 3] = c4.w;
                }
                cv[24] = csrow[24];
                #pragma unroll
                for (int c = 0; c < 25; ++c) {
                    v2f cs2; cs2[0] = cv[c]; cs2[1] = cv[c];
                    acc[c][0] = __builtin_elementwise_fma(xa, cs2, acc[c][0]);
                    acc[c][1] = __builtin_elementwise_fma(xb, cs2, acc[c][1]);
                }
            }
        }
    }

    if (active) {
        float* pb = ws + OFF_PART + (size_t)s * 51 * N;
        #pragma unroll
        for (int c = 0; c < 25; ++c) {
            float4 o;
            o.x = acc[c][0][0]; o.y = acc[c][0][1];
            o.z = acc[c][1][0]; o.w = acc[c][1][1];
            *(float4*)(pb + (size_t)(h * 25 + c) * N + n0) = o;
        }
        if (h == 0) {
            float4 tq;
            tq.x = tqa[0]; tq.y = tqa[1]; tq.z = tqb[0]; tq.w = tqb[1];
            *(float4*)(pb + (size_t)50 * N + n0) = tq;
        }
    }
}

// ---------------- K3b: block 0 = solve (gram sum, metrics, GJ, W8); blocks 1.. = reduce+keys ---
__global__ __launch_bounds__(256) void k3b_reduce(
    const float* __restrict__ concept, const float* __restrict__ hxw,
    float* __restrict__ ws, float* __restrict__ out)
{
    int t = threadIdx.x;

    if (blockIdx.x == 0) {
        // ---- solve role ----
        __shared__ float gsh[2500];
        __shared__ float A[50 * 56];     // [G | wc^T | pad]
        __shared__ float colp[C];
        __shared__ float part[3][4];
        int lane = t & 63, wid = t >> 6;

        if (t == 0) ((unsigned*)(ws + OFF_CNT))[0] = 0u;   // k4 completion counter

        float s_all = 0.f, s_tr = 0.f, s_abs = 0.f;
        for (int p = t; p < 2500; p += 256) {
            float g = 0.f;
            #pragma unroll
            for (int b = 0; b < KParts; ++b)
                g += ws[OFF_GPART + (size_t)b * 2500 + p];
            gsh[p] = g;
            int i = p / 50, jj = p - i * 50;
            float e = (i == jj) ? 1.0f : 0.0f;
            s_all += g;
            if (i == jj) s_tr += g;
            s_abs += fabsf(g - e);
        }
        #pragma unroll
        for (int off = 32; off > 0; off >>= 1) {
            s_all += __shfl_down(s_all, off, 64);
            s_tr  += __shfl_down(s_tr,  off, 64);
            s_abs += __shfl_down(s_abs, off, 64);
        }
        if (lane == 0) { part[0][wid] = s_all; part[1][wid] = s_tr; part[2][wid] = s_abs; }
        __syncthreads();
        if (t == 0) {
            float a  = part[0][0] + part[0][1] + part[0][2] + part[0][3];
            float tr = part[1][0] + part[1][1] + part[1][2] + part[1][3];
            float ab = part[2][0] + part[2][1] + part[2][2] + part[2][3];
            out[32769] = (a - tr) / 2500.0f;   // L_sparse_2
            out[32770] = tr / 2500.0f;         // norm_metrics
            out[32771] = ab / 2500.0f;         // similarity_penalty
        }

        for (int p = t; p < 50 * 56; p += 256) {
            int r = p / 56, col = p - r * 56;
            float v = 0.f;
            if (col < 50) v = gsh[r * 50 + col];
            else if (col < 54) {
                float w = 0.f;
                #pragma unroll
                for (int b = 0; b < KParts; ++b)
                    w += ws[OFF_WPART + (size_t)b * 200 + (col - 50) * 50 + r];
                v = w;
            }
            A[p] = v;
        }
        __syncthreads();

        // pivotless Gauss-Jordan (G is SPD -> stable without pivoting)
        for (int pc = 0; pc < C; ++pc) {
            if (t < C) colp[t] = A[t * 56 + pc];
            __syncthreads();
            float pinv = 1.0f / colp[pc];
            if (t < 56) A[pc * 56 + t] *= pinv;
            __syncthreads();
            for (int p = t; p < 50 * 56; p += 256) {
                int r = p / 56, col = p - r * 56;
                if (r != pc) A[p] = fmaf(-colp[r], A[pc * 56 + col], A[p]);
            }
            __syncthreads();
        }

        // W8[d][0..3] = hxw[j][d]; W8[d][4..7] = sum_c concept[d][c] * A[c][50+j]
        for (int d = t; d < D; d += 256) {
            float wy0 = 0.f, wy1 = 0.f, wy2 = 0.f, wy3 = 0.f;
            for (int c = 0; c < C; ++c) {
                float cv = concept[d * 50 + c];
                wy0 = fmaf(cv, A[c * 56 + 50], wy0);
                wy1 = fmaf(cv, A[c * 56 + 51], wy1);
                wy2 = fmaf(cv, A[c * 56 + 52], wy2);
                wy3 = fmaf(cv, A[c * 56 + 53], wy3);
            }
            float4 lo, hi;
            lo.x = hxw[0 * D + d]; lo.y = hxw[1 * D + d];
            lo.z = hxw[2 * D + d]; lo.w = hxw[3 * D + d];
            hi.x = wy0; hi.y = wy1; hi.z = wy2; hi.w = wy3;
            *(float4*)(ws + OFF_W8 + (size_t)d * 8)     = lo;
            *(float4*)(ws + OFF_W8 + (size_t)d * 8 + 4) = hi;
        }
        return;
    }

    // ---- reduce role: sum slab partials -> keys + tesq + per-wave range ----
    int rb = blockIdx.x - 1;          // 0..NB2-1
    int h = rb & 1;                   // c-half: 0 -> c 0..24, 1 -> c 25..49
    int n = (rb >> 1) * 256 + t;

    unsigned umin = 0xFFFFFFFFu, umax = 0u;
    if (n < N) {
        float tesq = ws[OFF_PART + (size_t)50 * N + n]
                   + ws[OFF_PART + ((size_t)51 + 50) * N + n];
        if (h == 0) ws[OFF_TESQ + n] = tesq;

        unsigned* uws = (unsigned*)ws;
        #pragma unroll
        for (int cc = 0; cc < 25; ++cc) {
            int c = h * 25 + cc;
            float dot = ws[OFF_PART + (size_t)c * N + n]
                      + ws[OFF_PART + ((size_t)51 + c) * N + n];
            unsigned u = keyu(dot, tesq);
            uws[(size_t)c * N + n] = u;
            umin = min(umin, u);
            umax = max(umax, u);
        }
    }
    #pragma unroll
    for (int off = 32; off > 0; off >>= 1) {
        umin = min(umin, (unsigned)__shfl_down((int)umin, off, 64));
        umax = max(umax, (unsigned)__shfl_down((int)umax, off, 64));
    }
    if ((t & 63) == 0) {
        int gw = rb * 4 + (t >> 6);
        ((unsigned*)(ws + OFF_RANGE))[2 * gw]     = umin;
        ((unsigned*)(ws + OFF_RANGE))[2 * gw + 1] = umax;
    }
}

// ---------------- Kpred: [orig_pred | y_pred] = X @ W8 + bias -----------------
__global__ __launch_bounds__(256) void kpred(
    const float* __restrict__ X, const float* __restrict__ hxb,
    const float* __restrict__ ws, float* __restrict__ out)
{
    int t = threadIdx.x;
    int lane = t & 63, w = t >> 6;
    int r = blockIdx.x * 4 + w;
    const float* xr = X + (size_t)r * D;
    const float* w8 = ws + OFF_W8;

    float acc[8];
    #pragma unroll
    for (int j = 0; j < 8; ++j) acc[j] = 0.f;
    #pragma unroll
    for (int i = 0; i < 16; ++i) {
        int d = i * 64 + lane;
        float x = xr[d];
        float4 lo = *(const float4*)(w8 + (size_t)d * 8);
        float4 hi = *(const float4*)(w8 + (size_t)d * 8 + 4);
        acc[0] = fmaf(x, lo.x, acc[0]);
        acc[1] = fmaf(x, lo.y, acc[1]);
        acc[2] = fmaf(x, lo.z, acc[2]);
        acc[3] = fmaf(x, lo.w, acc[3]);
        acc[4] = fmaf(x, hi.x, acc[4]);
        acc[5] = fmaf(x, hi.y, acc[5]);
        acc[6] = fmaf(x, hi.z, acc[6]);
        acc[7] = fmaf(x, hi.w, acc[7]);
    }
    #pragma unroll
    for (int j = 0; j < 8; ++j) {
        float v = acc[j];
        #pragma unroll
        for (int off = 32; off > 0; off >>= 1) v += __shfl_down(v, off, 64);
        if (lane == 0) {
            float b = hxb[j & 3];
            if (j < 4) out[(size_t)r * CLS + j] = v + b;
            else       out[16384 + (size_t)r * CLS + (j - 4)] = v + b;
        }
    }
}

// ---------------- K4: GR preamble + top-k from u keys + fused L_sparse_1 ------
__global__ __launch_bounds__(1024) void k4_select(
    const float* __restrict__ ws, float* __restrict__ wsw,
    float* __restrict__ out, const int* __restrict__ topk)
{
    int c = blockIdx.x, t = threadIdx.x;
    int lane = t & 63, wid = t >> 6;
    const unsigned* uarr = (const unsigned*)ws + (size_t)c * N;
    const float* tesq = ws + OFF_TESQ;

    __shared__ unsigned hist[4096];
    __shared__ unsigned wsum[16], woff[16];
    __shared__ unsigned wmn[16], wmx[16];
    __shared__ unsigned sh_ulo, sh_uhi;
    __shared__ unsigned sh_bin; __shared__ int sh_rem;
    __shared__ int cnt;
    __shared__ unsigned cand_u[CAP];
    __shared__ int      cand_i[CAP];
    __shared__ float fred[16];

    // ---- preamble: global key range from wave slots (redundant per block, exact) ----
    {
        const unsigned* rg = (const unsigned*)(ws + OFF_RANGE);
        unsigned mn = 0xFFFFFFFFu, mx = 0u;
        for (int i = t; i < NSLOT; i += 1024) {
            mn = min(mn, rg[2 * i]);
            mx = max(mx, rg[2 * i + 1]);
        }
        #pragma unroll
        for (int off = 32; off > 0; off >>= 1) {
            mn = min(mn, (unsigned)__shfl_down((int)mn, off, 64));
            mx = max(mx, (unsigned)__shfl_down((int)mx, off, 64));
        }
        if (lane == 0) { wmn[wid] = mn; wmx[wid] = mx; }
        __syncthreads();
        if (t == 0) {
            unsigned m0 = 0xFFFFFFFFu, m1 = 0u;
            for (int w = 0; w < 16; ++w) { m0 = min(m0, wmn[w]); m1 = max(m1, wmx[w]); }
            sh_ulo = m0; sh_uhi = m1;
        }
        __syncthreads();
    }
    unsigned ubase = sh_ulo;
    unsigned ulo = sh_ulo, uhi = sh_uhi;
    int rem = *topk;
    unsigned long long width = (unsigned long long)(uhi - ulo) + 1ull;

    // ---- pass 1: histogram over 4096 linear bins of the global range ----
    for (int i = t; i < 4096; i += 1024) hist[i] = 0u;
    __syncthreads();
    for (int n = t; n < N; n += 1024) {
        unsigned u = uarr[n];
        unsigned bin = (unsigned)(((unsigned long long)(u - ubase) * 4096ull) / width);
        atomicAdd(&hist[bin], 1u);
    }
    __syncthreads();
    {
        unsigned b0 = (unsigned)t * 4u;
        unsigned h0 = hist[b0], h1 = hist[b0 + 1], h2 = hist[b0 + 2], h3 = hist[b0 + 3];
        unsigned s4 = h0 + h1 + h2 + h3;
        unsigned x = s4;
        #pragma unroll
        for (int off = 1; off < 64; off <<= 1) {
            unsigned y = (unsigned)__shfl_up((int)x, off, 64);
            if (lane >= off) x += y;
        }
        if (lane == 63) wsum[wid] = x;
        __syncthreads();
        if (t == 0) {
            unsigned run = 0;
            for (int w = 0; w < 16; ++w) { woff[w] = run; run += wsum[w]; }
        }
        __syncthreads();
        unsigned cumBefore = woff[wid] + x - s4;
        unsigned remu = (unsigned)rem;
        if (cumBefore < remu && remu <= cumBefore + s4) {
            unsigned cum = cumBefore, bin = b0, r2 = 1;
            unsigned hh[4] = {h0, h1, h2, h3};
            #pragma unroll
            for (int j = 0; j < 4; ++j) {
                if (cum + hh[j] >= remu) { bin = b0 + j; r2 = remu - cum; break; }
                cum += hh[j];
            }
            sh_bin = bin; sh_rem = (int)r2;
        }
        __syncthreads();
        unsigned b = sh_bin;
        rem = sh_rem;
        ulo = ubase + (unsigned)(((unsigned long long)b * width + 4095ull) / 4096ull);
        uhi = ubase + (unsigned)((((unsigned long long)(b + 1) * width + 4095ull) / 4096ull) - 1ull);
        __syncthreads();
    }

    // ---- final: sum recovered dots below cutoff bin; collect cutoff-bin candidates ----
    if (t == 0) cnt = 0;
    __syncthreads();
    float lsum = 0.f;
    for (int n = t; n < N; n += 1024) {
        unsigned u = uarr[n];
        if (u < ulo) {
            lsum += 0.5f * (tesq[n] - unmapf(u));   // dot = (tesq - key)/2
        } else if (u <= uhi) {
            int s = atomicAdd(&cnt, 1);
            if (s < CAP) { cand_u[s] = u; cand_i[s] = n; }
        }
    }
    __syncthreads();
    int cc = cnt < CAP ? cnt : CAP;
    for (int ci = t; ci < cc; ci += 1024) {
        unsigned ui = cand_u[ci]; int ii = cand_i[ci];
        int rank = 0;
        for (int j = 0; j < cc; ++j) {
            unsigned uj = cand_u[j];
            rank += (uj < ui || (uj == ui && cand_i[j] < ii)) ? 1 : 0;
        }
        if (rank < rem) lsum += 0.5f * (tesq[ii] - unmapf(ui));
    }
    #pragma unroll
    for (int off = 32; off > 0; off >>= 1) lsum += __shfl_down(lsum, off, 64);
    if (lane == 0) fred[wid] = lsum;
    __syncthreads();
    if (t == 0) {
        float tot = 0.f;
        for (int w = 0; w < 16; ++w) tot += fred[w];
        wsw[OFF_SUMS + c] = tot;
        __threadfence();
        unsigned done = atomicAdd((unsigned*)(wsw + OFF_CNT), 1u);
        if (done == C - 1) {
            float s = 0.f;
            for (int i = 0; i < C; ++i) s += atomicAdd(&wsw[OFF_SUMS + i], 0.0f);
            out[32768] = s / (float)((*topk) * C);
        }
    }
}

extern "C" void kernel_launch(void* const* d_in, const int* in_sizes, int n_in,
                              void* d_out, int out_size, void* d_ws, size_t ws_size,
                              hipStream_t stream) {
    (void)in_sizes; (void)n_in; (void)out_size; (void)ws_size;
    const float* concept = (const float*)d_in[0];
    const float* te      = (const float*)d_in[1];
    const float* X       = (const float*)d_in[2];
    const float* hxw     = (const float*)d_in[3];
    const float* hxb     = (const float*)d_in[4];
    const int*   topk    = (const int*)d_in[5];
    float* out = (float*)d_out;
    float* ws  = (float*)d_ws;

    k3a_dots<<<dim3(KParts + NSLAB * 2 * NBC), dim3(256), 0, stream>>>(concept, te, hxw, ws);
    k3b_reduce<<<dim3(1 + NB2), dim3(256), 0, stream>>>(concept, hxw, ws, out);
    kpred<<<dim3(B / 4), dim3(256), 0, stream>>>(X, hxb, ws, out);
    k4_select<<<dim3(C), dim3(1024), 0, stream>>>(ws, ws, out, topk);
}

// Round 13
// 556.748 us; speedup vs baseline: 2.9603x; 1.6347x over previous
//
#include <hip/hip_runtime.h>
#include <stdint.h>

#define D 1024
#define N 200000
#define C 50
#define B 4096
#define CLS 4
#define KParts 16
#define CAP 4096
#define BN 512
#define NBLK 391                    // ceil(N/BN); 391*512 = 200192
#define NSLOT (NBLK * 8)            // per-wave key-range slots

typedef __attribute__((ext_vector_type(8))) short short8;
typedef __attribute__((ext_vector_type(4))) float f32x4;

// ws float offsets
static const size_t OFF_U     = 0;                          // C*N uints (keys)
static const size_t OFF_TESQ  = (size_t)C * N;              // N floats
static const size_t OFF_GPART = OFF_TESQ + N;               // KParts*2500
static const size_t OFF_WPART = OFF_GPART + KParts * 2500;  // KParts*200
static const size_t OFF_ABF   = ((OFF_WPART + KParts * 200 + 3) / 4) * 4;  // 65536 ushort = 32768 float slots
static const size_t OFF_RANGE = OFF_ABF + 32768;            // NSLOT*2 uints
static const size_t OFF_SUMS  = OFF_RANGE + 2 * NSLOT;      // C floats
static const size_t OFF_CNT   = OFF_SUMS + C;               // 1 uint
static const size_t OFF_W8    = ((OFF_CNT + 1 + 3) / 4) * 4; // D*8 floats

__device__ __forceinline__ unsigned mapf(float v) {
    unsigned u = __float_as_uint(v);
    return (u & 0x80000000u) ? ~u : (u | 0x80000000u);
}
__device__ __forceinline__ float unmapf(unsigned u) {
    unsigned b = (u & 0x80000000u) ? (u ^ 0x80000000u) : ~u;
    return __uint_as_float(b);
}
__device__ __forceinline__ unsigned keyu(float dot, float tesq) {
    return mapf(fmaf(-2.0f, dot, tesq));
}
__device__ __forceinline__ unsigned short f2bf(float f) {   // RNE fp32->bf16
    unsigned u = __float_as_uint(f);
    u += 0x7FFFu + ((u >> 16) & 1u);
    return (unsigned short)(u >> 16);
}
__device__ __forceinline__ float bf2f(unsigned short h) {
    return __uint_as_float((unsigned)h << 16);
}

// ---------------- Kprep: gram/wc partials (blocks 0..15) + A-bf16 pack (block 16) ----------
__global__ __launch_bounds__(256) void kprep(
    const float* __restrict__ concept, const float* __restrict__ hxw,
    float* __restrict__ ws)
{
    int t = threadIdx.x;

    if (blockIdx.x < KParts) {
        __shared__ __align__(16) float ct[64 * 50];
        __shared__ float hs[4 * 64];
        int bid = blockIdx.x;
        int d0 = bid * 64;

        for (int i = t; i < 64 * 50; i += 256) ct[i] = concept[d0 * 50 + i];
        {
            int j = t >> 6, dd = t & 63;
            hs[t] = hxw[j * D + d0 + dd];
        }
        __syncthreads();

        float* gp = ws + OFF_GPART + (size_t)bid * 2500;
        for (int p = t; p < 2500; p += 256) {
            int i = p / 50, j = p - i * 50;
            float acc = 0.f;
            #pragma unroll 8
            for (int dd = 0; dd < 64; ++dd)
                acc = fmaf(ct[dd * 50 + i], ct[dd * 50 + j], acc);
            gp[p] = acc;
        }
        float* wp = ws + OFF_WPART + (size_t)bid * 200;
        if (t < 200) {
            int j = t / 50, c = t - j * 50;
            float acc = 0.f;
            #pragma unroll 8
            for (int dd = 0; dd < 64; ++dd)
                acc = fmaf(hs[j * 64 + dd], ct[dd * 50 + c], acc);
            wp[t] = acc;
        }
        return;
    }

    // A-pack: Aprep[ks][g][m][j] = bf16(concept[ks*32+g*8+j][m]), m<50 else 0
    unsigned short* ap = (unsigned short*)(ws + OFF_ABF);
    for (int idx = t; idx < 8192; idx += 256) {
        int ks = idx >> 8;
        int g  = (idx >> 6) & 3;
        int m  = idx & 63;
        unsigned short v[8];
        #pragma unroll
        for (int j = 0; j < 8; ++j) {
            int k = ks * 32 + g * 8 + j;
            v[j] = (m < 50) ? f2bf(concept[k * 50 + m]) : (unsigned short)0;
        }
        uint4 pk;
        pk.x = (unsigned)v[0] | ((unsigned)v[1] << 16);
        pk.y = (unsigned)v[2] | ((unsigned)v[3] << 16);
        pk.z = (unsigned)v[4] | ((unsigned)v[5] << 16);
        pk.w = (unsigned)v[6] | ((unsigned)v[7] << 16);
        *(uint4*)(ap + (size_t)idx * 8) = pk;
    }
}

// ---------------- Kgemm: MFMA dots+keys+tesq (blocks 0..390) | solve (block 391) ----------
__global__ __launch_bounds__(512) void kgemm(
    const float* __restrict__ concept, const float* __restrict__ te,
    const float* __restrict__ hxw, float* __restrict__ ws,
    float* __restrict__ out)
{
    __shared__ unsigned Bl[16 * 516];                 // paired-k bf16 tile, padded
    __shared__ __align__(16) unsigned short Al[4 * 64 * 8];
    __shared__ float tsp[4][BN];
    __shared__ float tsf[BN];
    // solve-role LDS
    __shared__ float gsh[2500];
    __shared__ float Asv[50 * 56];
    __shared__ float colp[C];
    __shared__ float part[3][8];

    int t = threadIdx.x;
    int l = t & 63, w = t >> 6;

    if (blockIdx.x == NBLK) {
        // ---- solve role: gram sum, metrics, pivotless GJ on [G|wc^T], W8 ----
        if (t == 0) ((unsigned*)(ws + OFF_CNT))[0] = 0u;

        float s_all = 0.f, s_tr = 0.f, s_abs = 0.f;
        for (int p = t; p < 2500; p += 512) {
            float g = 0.f;
            #pragma unroll
            for (int b = 0; b < KParts; ++b)
                g += ws[OFF_GPART + (size_t)b * 2500 + p];
            gsh[p] = g;
            int i = p / 50, jj = p - i * 50;
            float e = (i == jj) ? 1.0f : 0.0f;
            s_all += g;
            if (i == jj) s_tr += g;
            s_abs += fabsf(g - e);
        }
        #pragma unroll
        for (int off = 32; off > 0; off >>= 1) {
            s_all += __shfl_down(s_all, off, 64);
            s_tr  += __shfl_down(s_tr,  off, 64);
            s_abs += __shfl_down(s_abs, off, 64);
        }
        if (l == 0) { part[0][w] = s_all; part[1][w] = s_tr; part[2][w] = s_abs; }
        __syncthreads();
        if (t == 0) {
            float a = 0.f, tr = 0.f, ab = 0.f;
            for (int i = 0; i < 8; ++i) { a += part[0][i]; tr += part[1][i]; ab += part[2][i]; }
            out[32769] = (a - tr) / 2500.0f;
            out[32770] = tr / 2500.0f;
            out[32771] = ab / 2500.0f;
        }

        for (int p = t; p < 50 * 56; p += 512) {
            int r = p / 56, col = p - r * 56;
            float v = 0.f;
            if (col < 50) v = gsh[r * 50 + col];
            else if (col < 54) {
                float ww = 0.f;
                #pragma unroll
                for (int b = 0; b < KParts; ++b)
                    ww += ws[OFF_WPART + (size_t)b * 200 + (col - 50) * 50 + r];
                v = ww;
            }
            Asv[p] = v;
        }
        __syncthreads();

        for (int pc = 0; pc < C; ++pc) {
            if (t < C) colp[t] = Asv[t * 56 + pc];
            __syncthreads();
            float pinv = 1.0f / colp[pc];
            if (t < 56) Asv[pc * 56 + t] *= pinv;
            __syncthreads();
            for (int p = t; p < 50 * 56; p += 512) {
                int r = p / 56, col = p - r * 56;
                if (r != pc) Asv[p] = fmaf(-colp[r], Asv[pc * 56 + col], Asv[p]);
            }
            __syncthreads();
        }

        for (int d = t; d < D; d += 512) {
            float wy0 = 0.f, wy1 = 0.f, wy2 = 0.f, wy3 = 0.f;
            for (int c = 0; c < C; ++c) {
                float cv = concept[d * 50 + c];
                wy0 = fmaf(cv, Asv[c * 56 + 50], wy0);
                wy1 = fmaf(cv, Asv[c * 56 + 51], wy1);
                wy2 = fmaf(cv, Asv[c * 56 + 52], wy2);
                wy3 = fmaf(cv, Asv[c * 56 + 53], wy3);
            }
            float4 lo, hi;
            lo.x = hxw[0 * D + d]; lo.y = hxw[1 * D + d];
            lo.z = hxw[2 * D + d]; lo.w = hxw[3 * D + d];
            hi.x = wy0; hi.y = wy1; hi.z = wy2; hi.w = wy3;
            *(float4*)(ws + OFF_W8 + (size_t)d * 8)     = lo;
            *(float4*)(ws + OFF_W8 + (size_t)d * 8 + 4) = hi;
        }
        return;
    }

    // ---- GEMM role ----
    int nbase = blockIdx.x * BN;
    int nq = t & 127, rp = t >> 7;
    int ncol0 = nbase + nq * 4;
    bool colv = (ncol0 < N);        // N%4==0 -> quad all-or-nothing

    f32x4 accf[4][4];
    #pragma unroll
    for (int mf = 0; mf < 4; ++mf)
        #pragma unroll
        for (int nf = 0; nf < 4; ++nf)
            accf[mf][nf] = (f32x4)(0.0f);
    float ts0 = 0.f, ts1 = 0.f, ts2 = 0.f, ts3 = 0.f;

    const unsigned short* ap = (const unsigned short*)(ws + OFF_ABF);
    int g = l >> 4;

    #pragma unroll 1
    for (int ks = 0; ks < 32; ++ks) {
        __syncthreads();
        // stage A tile (4 KB copy)
        if (t < 256) {
            uint4 av = *(const uint4*)(ap + ((size_t)ks * 256 + t) * 8);
            *(uint4*)(Al + t * 8) = av;
        }
        // stage B tile: 4 row-pairs per thread, convert fp32->bf16, pack (k even|odd)
        #pragma unroll
        for (int pi = 0; pi < 4; ++pi) {
            int pair = rp + pi * 4;             // kp 0..15
            int k0 = ks * 32 + pair * 2;
            float4 xa, xb;
            if (colv) {
                xa = *(const float4*)(te + (size_t)k0 * N + ncol0);
                xb = *(const float4*)(te + (size_t)(k0 + 1) * N + ncol0);
            } else {
                xa = make_float4(0.f, 0.f, 0.f, 0.f);
                xb = make_float4(0.f, 0.f, 0.f, 0.f);
            }
            unsigned short a0 = f2bf(xa.x), a1 = f2bf(xa.y), a2 = f2bf(xa.z), a3 = f2bf(xa.w);
            unsigned short b0 = f2bf(xb.x), b1 = f2bf(xb.y), b2 = f2bf(xb.z), b3 = f2bf(xb.w);
            float fa0 = bf2f(a0), fa1 = bf2f(a1), fa2 = bf2f(a2), fa3 = bf2f(a3);
            float fb0 = bf2f(b0), fb1 = bf2f(b1), fb2 = bf2f(b2), fb3 = bf2f(b3);
            ts0 = fmaf(fa0, fa0, fmaf(fb0, fb0, ts0));
            ts1 = fmaf(fa1, fa1, fmaf(fb1, fb1, ts1));
            ts2 = fmaf(fa2, fa2, fmaf(fb2, fb2, ts2));
            ts3 = fmaf(fa3, fa3, fmaf(fb3, fb3, ts3));
            uint4 pk;
            pk.x = (unsigned)a0 | ((unsigned)b0 << 16);
            pk.y = (unsigned)a1 | ((unsigned)b1 << 16);
            pk.z = (unsigned)a2 | ((unsigned)b2 << 16);
            pk.w = (unsigned)a3 | ((unsigned)b3 << 16);
            *(uint4*)(&Bl[pair * 516 + nq * 4]) = pk;
        }
        __syncthreads();

        // MFMA: 4 m-frags x 4 n-frags per wave
        short8 af[4];
        #pragma unroll
        for (int mf = 0; mf < 4; ++mf)
            af[mf] = *(const short8*)(Al + ((size_t)(g * 64 + mf * 16 + (l & 15))) * 8);
        #pragma unroll
        for (int nf = 0; nf < 4; ++nf) {
            int nn = w * 64 + nf * 16 + (l & 15);
            union { unsigned u[4]; short8 s; } bu;
            bu.u[0] = Bl[(g * 4 + 0) * 516 + nn];
            bu.u[1] = Bl[(g * 4 + 1) * 516 + nn];
            bu.u[2] = Bl[(g * 4 + 2) * 516 + nn];
            bu.u[3] = Bl[(g * 4 + 3) * 516 + nn];
            short8 bv = bu.s;
            #pragma unroll
            for (int mf = 0; mf < 4; ++mf)
                accf[mf][nf] = __builtin_amdgcn_mfma_f32_16x16x32_bf16(
                    af[mf], bv, accf[mf][nf], 0, 0, 0);
        }
    }

    // tesq reduce across the 4 rp groups
    __syncthreads();
    tsp[rp][nq * 4 + 0] = ts0;
    tsp[rp][nq * 4 + 1] = ts1;
    tsp[rp][nq * 4 + 2] = ts2;
    tsp[rp][nq * 4 + 3] = ts3;
    __syncthreads();
    if (t < 128) {
        float4 s;
        s.x = tsp[0][t * 4 + 0] + tsp[1][t * 4 + 0] + tsp[2][t * 4 + 0] + tsp[3][t * 4 + 0];
        s.y = tsp[0][t * 4 + 1] + tsp[1][t * 4 + 1] + tsp[2][t * 4 + 1] + tsp[3][t * 4 + 1];
        s.z = tsp[0][t * 4 + 2] + tsp[1][t * 4 + 2] + tsp[2][t * 4 + 2] + tsp[3][t * 4 + 2];
        s.w = tsp[0][t * 4 + 3] + tsp[1][t * 4 + 3] + tsp[2][t * 4 + 3] + tsp[3][t * 4 + 3];
        *(float4*)(&tsf[t * 4]) = s;
        if (nbase + t * 4 < N)
            *(float4*)(ws + OFF_TESQ + nbase + t * 4) = s;
    }
    __syncthreads();

    // epilogue: keys + per-wave range
    unsigned* uws = (unsigned*)ws;
    unsigned kmin = 0xFFFFFFFFu, kmax = 0u;
    #pragma unroll
    for (int mf = 0; mf < 4; ++mf) {
        #pragma unroll
        for (int nf = 0; nf < 4; ++nf) {
            int nloc = w * 64 + nf * 16 + (l & 15);
            int nabs = nbase + nloc;
            #pragma unroll
            for (int r = 0; r < 4; ++r) {
                int c = mf * 16 + (l >> 4) * 4 + r;   // C/D row map (m89-verified)
                if (c < 50 && nabs < N) {
                    unsigned u = keyu(accf[mf][nf][r], tsf[nloc]);
                    uws[(size_t)c * N + nabs] = u;
                    kmin = min(kmin, u);
                    kmax = max(kmax, u);
                }
            }
        }
    }
    #pragma unroll
    for (int off = 32; off > 0; off >>= 1) {
        kmin = min(kmin, (unsigned)__shfl_down((int)kmin, off, 64));
        kmax = max(kmax, (unsigned)__shfl_down((int)kmax, off, 64));
    }
    if (l == 0) {
        int slot = blockIdx.x * 8 + w;
        ((unsigned*)(ws + OFF_RANGE))[2 * slot]     = kmin;
        ((unsigned*)(ws + OFF_RANGE))[2 * slot + 1] = kmax;
    }
}

// ---------------- Kpred: [orig_pred | y_pred] = X @ W8 + bias -----------------
__global__ __launch_bounds__(256) void kpred(
    const float* __restrict__ X, const float* __restrict__ hxb,
    const float* __restrict__ ws, float* __restrict__ out)
{
    int t = threadIdx.x;
    int lane = t & 63, w = t >> 6;
    int r = blockIdx.x * 4 + w;
    const float* xr = X + (size_t)r * D;
    const float* w8 = ws + OFF_W8;

    float acc[8];
    #pragma unroll
    for (int j = 0; j < 8; ++j) acc[j] = 0.f;
    #pragma unroll
    for (int i = 0; i < 16; ++i) {
        int d = i * 64 + lane;
        float x = xr[d];
        float4 lo = *(const float4*)(w8 + (size_t)d * 8);
        float4 hi = *(const float4*)(w8 + (size_t)d * 8 + 4);
        acc[0] = fmaf(x, lo.x, acc[0]);
        acc[1] = fmaf(x, lo.y, acc[1]);
        acc[2] = fmaf(x, lo.z, acc[2]);
        acc[3] = fmaf(x, lo.w, acc[3]);
        acc[4] = fmaf(x, hi.x, acc[4]);
        acc[5] = fmaf(x, hi.y, acc[5]);
        acc[6] = fmaf(x, hi.z, acc[6]);
        acc[7] = fmaf(x, hi.w, acc[7]);
    }
    #pragma unroll
    for (int j = 0; j < 8; ++j) {
        float v = acc[j];
        #pragma unroll
        for (int off = 32; off > 0; off >>= 1) v += __shfl_down(v, off, 64);
        if (lane == 0) {
            float b = hxb[j & 3];
            if (j < 4) out[(size_t)r * CLS + j] = v + b;
            else       out[16384 + (size_t)r * CLS + (j - 4)] = v + b;
        }
    }
}

// ---------------- K4: GR preamble + top-k from u keys + fused L_sparse_1 ------
__global__ __launch_bounds__(1024) void k4_select(
    const float* __restrict__ ws, float* __restrict__ wsw,
    float* __restrict__ out, const int* __restrict__ topk)
{
    int c = blockIdx.x, t = threadIdx.x;
    int lane = t & 63, wid = t >> 6;
    const unsigned* uarr = (const unsigned*)ws + (size_t)c * N;
    const float* tesq = ws + OFF_TESQ;

    __shared__ unsigned hist[4096];
    __shared__ unsigned wsum[16], woff[16];
    __shared__ unsigned wmn[16], wmx[16];
    __shared__ unsigned sh_ulo, sh_uhi;
    __shared__ unsigned sh_bin; __shared__ int sh_rem;
    __shared__ int cnt;
    __shared__ unsigned cand_u[CAP];
    __shared__ int      cand_i[CAP];
    __shared__ float fred[16];

    // preamble: global key range from wave slots
    {
        const unsigned* rg = (const unsigned*)(ws + OFF_RANGE);
        unsigned mn = 0xFFFFFFFFu, mx = 0u;
        for (int i = t; i < NSLOT; i += 1024) {
            mn = min(mn, rg[2 * i]);
            mx = max(mx, rg[2 * i + 1]);
        }
        #pragma unroll
        for (int off = 32; off > 0; off >>= 1) {
            mn = min(mn, (unsigned)__shfl_down((int)mn, off, 64));
            mx = max(mx, (unsigned)__shfl_down((int)mx, off, 64));
        }
        if (lane == 0) { wmn[wid] = mn; wmx[wid] = mx; }
        __syncthreads();
        if (t == 0) {
            unsigned m0 = 0xFFFFFFFFu, m1 = 0u;
            for (int w = 0; w < 16; ++w) { m0 = min(m0, wmn[w]); m1 = max(m1, wmx[w]); }
            sh_ulo = m0; sh_uhi = m1;
        }
        __syncthreads();
    }
    unsigned ubase = sh_ulo;
    unsigned ulo = sh_ulo, uhi = sh_uhi;
    int rem = *topk;
    unsigned long long width = (unsigned long long)(uhi - ulo) + 1ull;

    // pass 1: histogram over 4096 linear bins
    for (int i = t; i < 4096; i += 1024) hist[i] = 0u;
    __syncthreads();
    for (int n = t; n < N; n += 1024) {
        unsigned u = uarr[n];
        unsigned bin = (unsigned)(((unsigned long long)(u - ubase) * 4096ull) / width);
        atomicAdd(&hist[bin], 1u);
    }
    __syncthreads();
    {
        unsigned b0 = (unsigned)t * 4u;
        unsigned h0 = hist[b0], h1 = hist[b0 + 1], h2 = hist[b0 + 2], h3 = hist[b0 + 3];
        unsigned s4 = h0 + h1 + h2 + h3;
        unsigned x = s4;
        #pragma unroll
        for (int off = 1; off < 64; off <<= 1) {
            unsigned y = (unsigned)__shfl_up((int)x, off, 64);
            if (lane >= off) x += y;
        }
        if (lane == 63) wsum[wid] = x;
        __syncthreads();
        if (t == 0) {
            unsigned run = 0;
            for (int w = 0; w < 16; ++w) { woff[w] = run; run += wsum[w]; }
        }
        __syncthreads();
        unsigned cumBefore = woff[wid] + x - s4;
        unsigned remu = (unsigned)rem;
        if (cumBefore < remu && remu <= cumBefore + s4) {
            unsigned cum = cumBefore, bin = b0, r2 = 1;
            unsigned hh[4] = {h0, h1, h2, h3};
            #pragma unroll
            for (int j = 0; j < 4; ++j) {
                if (cum + hh[j] >= remu) { bin = b0 + j; r2 = remu - cum; break; }
                cum += hh[j];
            }
            sh_bin = bin; sh_rem = (int)r2;
        }
        __syncthreads();
        unsigned b = sh_bin;
        rem = sh_rem;
        ulo = ubase + (unsigned)(((unsigned long long)b * width + 4095ull) / 4096ull);
        uhi = ubase + (unsigned)((((unsigned long long)(b + 1) * width + 4095ull) / 4096ull) - 1ull);
        __syncthreads();
    }

    // final: sum recovered dots below cutoff bin; collect cutoff-bin candidates
    if (t == 0) cnt = 0;
    __syncthreads();
    float lsum = 0.f;
    for (int n = t; n < N; n += 1024) {
        unsigned u = uarr[n];
        if (u < ulo) {
            lsum += 0.5f * (tesq[n] - unmapf(u));
        } else if (u <= uhi) {
            int s = atomicAdd(&cnt, 1);
            if (s < CAP) { cand_u[s] = u; cand_i[s] = n; }
        }
    }
    __syncthreads();
    int cc = cnt < CAP ? cnt : CAP;
    for (int ci = t; ci < cc; ci += 1024) {
        unsigned ui = cand_u[ci]; int ii = cand_i[ci];
        int rank = 0;
        for (int j = 0; j < cc; ++j) {
            unsigned uj = cand_u[j];
            rank += (uj < ui || (uj == ui && cand_i[j] < ii)) ? 1 : 0;
        }
        if (rank < rem) lsum += 0.5f * (tesq[ii] - unmapf(ui));
    }
    #pragma unroll
    for (int off = 32; off > 0; off >>= 1) lsum += __shfl_down(lsum, off, 64);
    if (lane == 0) fred[wid] = lsum;
    __syncthreads();
    if (t == 0) {
        float tot = 0.f;
        for (int w = 0; w < 16; ++w) tot += fred[w];
        wsw[OFF_SUMS + c] = tot;
        __threadfence();
        unsigned done = atomicAdd((unsigned*)(wsw + OFF_CNT), 1u);
        if (done == C - 1) {
            float s = 0.f;
            for (int i = 0; i < C; ++i) s += atomicAdd(&wsw[OFF_SUMS + i], 0.0f);
            out[32768] = s / (float)((*topk) * C);
        }
    }
}

extern "C" void kernel_launch(void* const* d_in, const int* in_sizes, int n_in,
                              void* d_out, int out_size, void* d_ws, size_t ws_size,
                              hipStream_t stream) {
    (void)in_sizes; (void)n_in; (void)out_size; (void)ws_size;
    const float* concept = (const float*)d_in[0];
    const float* te      = (const float*)d_in[1];
    const float* X       = (const float*)d_in[2];
    const float* hxw     = (const float*)d_in[3];
    const float* hxb     = (const float*)d_in[4];
    const int*   topk    = (const int*)d_in[5];
    float* out = (float*)d_out;
    float* ws  = (float*)d_ws;

    kprep<<<dim3(KParts + 1), dim3(256), 0, stream>>>(concept, hxw, ws);
    kgemm<<<dim3(NBLK + 1), dim3(512), 0, stream>>>(concept, te, hxw, ws, out);
    kpred<<<dim3(B / 4), dim3(256), 0, stream>>>(X, hxb, ws, out);
    k4_select<<<dim3(C), dim3(1024), 0, stream>>>(ws, ws, out, topk);
}

// Round 14
// 508.996 us; speedup vs baseline: 3.2380x; 1.0938x over previous
//
#include <hip/hip_runtime.h>
#include <stdint.h>

#define D 1024
#define N 200000
#define C 50
#define B 4096
#define CLS 4
#define KParts 16
#define CAP 4096
#define BN 256
#define NBLK 782                    // ceil(N/BN); 782*256 = 200192
#define NSLOT (NBLK * 8)            // per-wave key-range slots
#define BLROW 260                   // padded row (u32) of B tile

typedef __attribute__((ext_vector_type(8))) short short8;
typedef __attribute__((ext_vector_type(4))) float f32x4;

// ws float offsets
static const size_t OFF_U     = 0;                          // C*N uints (keys)
static const size_t OFF_TESQ  = (size_t)C * N;              // N floats
static const size_t OFF_GPART = OFF_TESQ + N;               // KParts*2500
static const size_t OFF_WPART = OFF_GPART + KParts * 2500;  // KParts*200
static const size_t OFF_ABF   = ((OFF_WPART + KParts * 200 + 3) / 4) * 4;  // 65536 ushort
static const size_t OFF_RANGE = OFF_ABF + 32768;            // NSLOT*2 uints
static const size_t OFF_SUMS  = OFF_RANGE + 2 * NSLOT;      // C floats
static const size_t OFF_CNT   = OFF_SUMS + C;               // 1 uint
static const size_t OFF_W8    = ((OFF_CNT + 1 + 3) / 4) * 4; // D*8 floats

__device__ __forceinline__ unsigned mapf(float v) {
    unsigned u = __float_as_uint(v);
    return (u & 0x80000000u) ? ~u : (u | 0x80000000u);
}
__device__ __forceinline__ float unmapf(unsigned u) {
    unsigned b = (u & 0x80000000u) ? (u ^ 0x80000000u) : ~u;
    return __uint_as_float(b);
}
__device__ __forceinline__ unsigned keyu(float dot, float tesq) {
    return mapf(fmaf(-2.0f, dot, tesq));
}
__device__ __forceinline__ unsigned short f2bf(float f) {   // RNE fp32->bf16
    unsigned u = __float_as_uint(f);
    u += 0x7FFFu + ((u >> 16) & 1u);
    return (unsigned short)(u >> 16);
}
__device__ __forceinline__ float bf2f(unsigned short h) {
    return __uint_as_float((unsigned)h << 16);
}

// ---------------- Kprep: gram/wc partials (blocks 0..15) + A-bf16 pack (block 16) ----------
__global__ __launch_bounds__(256) void kprep(
    const float* __restrict__ concept, const float* __restrict__ hxw,
    float* __restrict__ ws)
{
    int t = threadIdx.x;

    if (blockIdx.x < KParts) {
        __shared__ __align__(16) float ct[64 * 50];
        __shared__ float hs[4 * 64];
        int bid = blockIdx.x;
        int d0 = bid * 64;

        for (int i = t; i < 64 * 50; i += 256) ct[i] = concept[d0 * 50 + i];
        {
            int j = t >> 6, dd = t & 63;
            hs[t] = hxw[j * D + d0 + dd];
        }
        __syncthreads();

        float* gp = ws + OFF_GPART + (size_t)bid * 2500;
        for (int p = t; p < 2500; p += 256) {
            int i = p / 50, j = p - i * 50;
            float acc = 0.f;
            #pragma unroll 8
            for (int dd = 0; dd < 64; ++dd)
                acc = fmaf(ct[dd * 50 + i], ct[dd * 50 + j], acc);
            gp[p] = acc;
        }
        float* wp = ws + OFF_WPART + (size_t)bid * 200;
        if (t < 200) {
            int j = t / 50, c = t - j * 50;
            float acc = 0.f;
            #pragma unroll 8
            for (int dd = 0; dd < 64; ++dd)
                acc = fmaf(hs[j * 64 + dd], ct[dd * 50 + c], acc);
            wp[t] = acc;
        }
        return;
    }

    // A-pack: ap[((ks*4+g)*64 + m)*8 + j] = bf16(concept[ks*32+g*8+j][m]), m<50 else 0
    unsigned short* ap = (unsigned short*)(ws + OFF_ABF);
    for (int idx = t; idx < 8192; idx += 256) {
        int ks = idx >> 8;
        int g  = (idx >> 6) & 3;
        int m  = idx & 63;
        unsigned short v[8];
        #pragma unroll
        for (int j = 0; j < 8; ++j) {
            int k = ks * 32 + g * 8 + j;
            v[j] = (m < 50) ? f2bf(concept[k * 50 + m]) : (unsigned short)0;
        }
        uint4 pk;
        pk.x = (unsigned)v[0] | ((unsigned)v[1] << 16);
        pk.y = (unsigned)v[2] | ((unsigned)v[3] << 16);
        pk.z = (unsigned)v[4] | ((unsigned)v[5] << 16);
        pk.w = (unsigned)v[6] | ((unsigned)v[7] << 16);
        *(uint4*)(ap + (size_t)idx * 8) = pk;
    }
}

// ---------------- Kgemm: MFMA dots+keys+tesq (blocks 0..781) | solve (block 782) ----------
__global__ __launch_bounds__(512, 4) void kgemm(
    const float* __restrict__ concept, const float* __restrict__ te,
    const float* __restrict__ hxw, float* __restrict__ ws,
    float* __restrict__ out)
{
    __shared__ __align__(16) unsigned char smem[42496];

    int t = threadIdx.x;
    int l = t & 63, w = t >> 6;

    if (blockIdx.x == NBLK) {
        // ---- solve role: gram sum, metrics, pivotless GJ on [G|wc^T], W8 ----
        float* gsh  = (float*)smem;             // 2500
        float* Asv  = (float*)(smem + 10000);   // 50*56
        float* colp = (float*)(smem + 21200);   // 50
        float* part = (float*)(smem + 21408);   // 3*8

        if (t == 0) ((unsigned*)(ws + OFF_CNT))[0] = 0u;

        float s_all = 0.f, s_tr = 0.f, s_abs = 0.f;
        for (int p = t; p < 2500; p += 512) {
            float g = 0.f;
            #pragma unroll
            for (int b = 0; b < KParts; ++b)
                g += ws[OFF_GPART + (size_t)b * 2500 + p];
            gsh[p] = g;
            int i = p / 50, jj = p - i * 50;
            float e = (i == jj) ? 1.0f : 0.0f;
            s_all += g;
            if (i == jj) s_tr += g;
            s_abs += fabsf(g - e);
        }
        #pragma unroll
        for (int off = 32; off > 0; off >>= 1) {
            s_all += __shfl_down(s_all, off, 64);
            s_tr  += __shfl_down(s_tr,  off, 64);
            s_abs += __shfl_down(s_abs, off, 64);
        }
        if (l == 0) { part[0 * 8 + w] = s_all; part[1 * 8 + w] = s_tr; part[2 * 8 + w] = s_abs; }
        __syncthreads();
        if (t == 0) {
            float a = 0.f, tr = 0.f, ab = 0.f;
            for (int i = 0; i < 8; ++i) {
                a += part[0 * 8 + i]; tr += part[1 * 8 + i]; ab += part[2 * 8 + i];
            }
            out[32769] = (a - tr) / 2500.0f;
            out[32770] = tr / 2500.0f;
            out[32771] = ab / 2500.0f;
        }

        for (int p = t; p < 50 * 56; p += 512) {
            int r = p / 56, col = p - r * 56;
            float v = 0.f;
            if (col < 50) v = gsh[r * 50 + col];
            else if (col < 54) {
                float ww = 0.f;
                #pragma unroll
                for (int b = 0; b < KParts; ++b)
                    ww += ws[OFF_WPART + (size_t)b * 200 + (col - 50) * 50 + r];
                v = ww;
            }
            Asv[p] = v;
        }
        __syncthreads();

        for (int pc = 0; pc < C; ++pc) {
            if (t < C) colp[t] = Asv[t * 56 + pc];
            __syncthreads();
            float pinv = 1.0f / colp[pc];
            if (t < 56) Asv[pc * 56 + t] *= pinv;
            __syncthreads();
            for (int p = t; p < 50 * 56; p += 512) {
                int r = p / 56, col = p - r * 56;
                if (r != pc) Asv[p] = fmaf(-colp[r], Asv[pc * 56 + col], Asv[p]);
            }
            __syncthreads();
        }

        for (int d = t; d < D; d += 512) {
            float wy0 = 0.f, wy1 = 0.f, wy2 = 0.f, wy3 = 0.f;
            for (int c = 0; c < C; ++c) {
                float cv = concept[d * 50 + c];
                wy0 = fmaf(cv, Asv[c * 56 + 50], wy0);
                wy1 = fmaf(cv, Asv[c * 56 + 51], wy1);
                wy2 = fmaf(cv, Asv[c * 56 + 52], wy2);
                wy3 = fmaf(cv, Asv[c * 56 + 53], wy3);
            }
            float4 lo, hi;
            lo.x = hxw[0 * D + d]; lo.y = hxw[1 * D + d];
            lo.z = hxw[2 * D + d]; lo.w = hxw[3 * D + d];
            hi.x = wy0; hi.y = wy1; hi.z = wy2; hi.w = wy3;
            *(float4*)(ws + OFF_W8 + (size_t)d * 8)     = lo;
            *(float4*)(ws + OFF_W8 + (size_t)d * 8 + 4) = hi;
        }
        return;
    }

    // ---- GEMM role ----
    unsigned* Blb = (unsigned*)smem;                  // [2][16*260]
    float* tsp = (float*)(smem + 33280);              // [8][256]
    float* tsf = (float*)(smem + 33280 + 8192);       // [256]

    int nbase = blockIdx.x * BN;
    int nq = t & 63, rp = w;                          // quad in tile, pair-group = wave id
    int ncol0 = nbase + nq * 4;
    bool colv = (ncol0 < N);

    f32x4 accf[2][4];
    #pragma unroll
    for (int mf = 0; mf < 2; ++mf)
        #pragma unroll
        for (int nf = 0; nf < 4; ++nf)
            accf[mf][nf] = (f32x4)(0.0f);
    float ts0 = 0.f, ts1 = 0.f, ts2 = 0.f, ts3 = 0.f;

    const unsigned short* ap = (const unsigned short*)(ws + OFF_ABF);
    int g = l >> 4;
    int mhalf = w >> 2;
    int nnb = (w & 3) * 64 + (l & 15);

    // ---- convert+write macro body (tile ks -> buffer buf) ----
    auto cvt_write = [&](int buf, float4* xr) {
        #pragma unroll
        for (int pi = 0; pi < 2; ++pi) {
            int pair = rp + pi * 8;
            float4 xa = xr[2 * pi], xb = xr[2 * pi + 1];
            unsigned short a0 = f2bf(xa.x), a1 = f2bf(xa.y), a2 = f2bf(xa.z), a3 = f2bf(xa.w);
            unsigned short b0 = f2bf(xb.x), b1 = f2bf(xb.y), b2 = f2bf(xb.z), b3 = f2bf(xb.w);
            float fa0 = bf2f(a0), fa1 = bf2f(a1), fa2 = bf2f(a2), fa3 = bf2f(a3);
            float fb0 = bf2f(b0), fb1 = bf2f(b1), fb2 = bf2f(b2), fb3 = bf2f(b3);
            ts0 = fmaf(fa0, fa0, fmaf(fb0, fb0, ts0));
            ts1 = fmaf(fa1, fa1, fmaf(fb1, fb1, ts1));
            ts2 = fmaf(fa2, fa2, fmaf(fb2, fb2, ts2));
            ts3 = fmaf(fa3, fa3, fmaf(fb3, fb3, ts3));
            uint4 pk;
            pk.x = (unsigned)a0 | ((unsigned)b0 << 16);
            pk.y = (unsigned)a1 | ((unsigned)b1 << 16);
            pk.z = (unsigned)a2 | ((unsigned)b2 << 16);
            pk.w = (unsigned)a3 | ((unsigned)b3 << 16);
            *(uint4*)(&Blb[buf * (16 * BLROW) + pair * BLROW + nq * 4]) = pk;
        }
    };
    auto ldtile = [&](int ks, float4* xr) {
        #pragma unroll
        for (int pi = 0; pi < 2; ++pi) {
            int pair = rp + pi * 8;
            int k0 = ks * 32 + pair * 2;
            if (colv) {
                xr[2 * pi]     = *(const float4*)(te + (size_t)k0 * N + ncol0);
                xr[2 * pi + 1] = *(const float4*)(te + (size_t)(k0 + 1) * N + ncol0);
            } else {
                xr[2 * pi]     = make_float4(0.f, 0.f, 0.f, 0.f);
                xr[2 * pi + 1] = make_float4(0.f, 0.f, 0.f, 0.f);
            }
        }
    };

    // prologue: tile 0 -> Bl[0]
    {
        float4 xr[4];
        ldtile(0, xr);
        cvt_write(0, xr);
    }

    #pragma unroll 1
    for (int ks = 0; ks < 32; ++ks) {
        __syncthreads();                      // Bl[ks&1] ready; prior reads of Bl[(ks&1)^1] done
        float4 nx[4];
        if (ks < 31) ldtile(ks + 1, nx);      // issue early; consumed after MFMAs

        // A-frags direct from global (L2-resident)
        short8 af0 = *(const short8*)(ap + ((size_t)(ks * 4 + g) * 64 + mhalf * 32 + 0 * 16 + (l & 15)) * 8);
        short8 af1 = *(const short8*)(ap + ((size_t)(ks * 4 + g) * 64 + mhalf * 32 + 1 * 16 + (l & 15)) * 8);

        const unsigned* Bc = Blb + (ks & 1) * (16 * BLROW);
        #pragma unroll
        for (int nf = 0; nf < 4; ++nf) {
            int nn = nnb + nf * 16;
            union { unsigned u[4]; short8 s; } bu;
            bu.u[0] = Bc[(g * 4 + 0) * BLROW + nn];
            bu.u[1] = Bc[(g * 4 + 1) * BLROW + nn];
            bu.u[2] = Bc[(g * 4 + 2) * BLROW + nn];
            bu.u[3] = Bc[(g * 4 + 3) * BLROW + nn];
            accf[0][nf] = __builtin_amdgcn_mfma_f32_16x16x32_bf16(af0, bu.s, accf[0][nf], 0, 0, 0);
            accf[1][nf] = __builtin_amdgcn_mfma_f32_16x16x32_bf16(af1, bu.s, accf[1][nf], 0, 0, 0);
        }

        if (ks < 31) cvt_write((ks + 1) & 1, nx);
    }

    // tesq reduce across the 8 pair-groups
    __syncthreads();
    tsp[rp * 256 + nq * 4 + 0] = ts0;
    tsp[rp * 256 + nq * 4 + 1] = ts1;
    tsp[rp * 256 + nq * 4 + 2] = ts2;
    tsp[rp * 256 + nq * 4 + 3] = ts3;
    __syncthreads();
    if (t < 64) {
        float4 s = make_float4(0.f, 0.f, 0.f, 0.f);
        #pragma unroll
        for (int r = 0; r < 8; ++r) {
            float4 v = *(const float4*)(&tsp[r * 256 + t * 4]);
            s.x += v.x; s.y += v.y; s.z += v.z; s.w += v.w;
        }
        *(float4*)(&tsf[t * 4]) = s;
        if (nbase + t * 4 < N)
            *(float4*)(ws + OFF_TESQ + nbase + t * 4) = s;
    }
    __syncthreads();

    // epilogue: keys + per-wave range
    unsigned* uws = (unsigned*)ws;
    unsigned kmin = 0xFFFFFFFFu, kmax = 0u;
    #pragma unroll
    for (int mf = 0; mf < 2; ++mf) {
        #pragma unroll
        for (int nf = 0; nf < 4; ++nf) {
            int nloc = nnb + nf * 16;
            int nabs = nbase + nloc;
            #pragma unroll
            for (int r = 0; r < 4; ++r) {
                int c = mhalf * 32 + mf * 16 + (l >> 4) * 4 + r;   // C/D row map (m89)
                if (c < 50 && nabs < N) {
                    unsigned u = keyu(accf[mf][nf][r], tsf[nloc]);
                    uws[(size_t)c * N + nabs] = u;
                    kmin = min(kmin, u);
                    kmax = max(kmax, u);
                }
            }
        }
    }
    #pragma unroll
    for (int off = 32; off > 0; off >>= 1) {
        kmin = min(kmin, (unsigned)__shfl_down((int)kmin, off, 64));
        kmax = max(kmax, (unsigned)__shfl_down((int)kmax, off, 64));
    }
    if (l == 0) {
        int slot = blockIdx.x * 8 + w;
        ((unsigned*)(ws + OFF_RANGE))[2 * slot]     = kmin;
        ((unsigned*)(ws + OFF_RANGE))[2 * slot + 1] = kmax;
    }
}

// ---------------- Kpred: [orig_pred | y_pred] = X @ W8 + bias -----------------
__global__ __launch_bounds__(256) void kpred(
    const float* __restrict__ X, const float* __restrict__ hxb,
    const float* __restrict__ ws, float* __restrict__ out)
{
    int t = threadIdx.x;
    int lane = t & 63, w = t >> 6;
    int r = blockIdx.x * 4 + w;
    const float* xr = X + (size_t)r * D;
    const float* w8 = ws + OFF_W8;

    float acc[8];
    #pragma unroll
    for (int j = 0; j < 8; ++j) acc[j] = 0.f;
    #pragma unroll
    for (int i = 0; i < 16; ++i) {
        int d = i * 64 + lane;
        float x = xr[d];
        float4 lo = *(const float4*)(w8 + (size_t)d * 8);
        float4 hi = *(const float4*)(w8 + (size_t)d * 8 + 4);
        acc[0] = fmaf(x, lo.x, acc[0]);
        acc[1] = fmaf(x, lo.y, acc[1]);
        acc[2] = fmaf(x, lo.z, acc[2]);
        acc[3] = fmaf(x, lo.w, acc[3]);
        acc[4] = fmaf(x, hi.x, acc[4]);
        acc[5] = fmaf(x, hi.y, acc[5]);
        acc[6] = fmaf(x, hi.z, acc[6]);
        acc[7] = fmaf(x, hi.w, acc[7]);
    }
    #pragma unroll
    for (int j = 0; j < 8; ++j) {
        float v = acc[j];
        #pragma unroll
        for (int off = 32; off > 0; off >>= 1) v += __shfl_down(v, off, 64);
        if (lane == 0) {
            float b = hxb[j & 3];
            if (j < 4) out[(size_t)r * CLS + j] = v + b;
            else       out[16384 + (size_t)r * CLS + (j - 4)] = v + b;
        }
    }
}

// ---------------- K4: GR preamble + top-k from u keys + fused L_sparse_1 ------
__global__ __launch_bounds__(1024) void k4_select(
    const float* __restrict__ ws, float* __restrict__ wsw,
    float* __restrict__ out, const int* __restrict__ topk)
{
    int c = blockIdx.x, t = threadIdx.x;
    int lane = t & 63, wid = t >> 6;
    const unsigned* uarr = (const unsigned*)ws + (size_t)c * N;
    const float* tesq = ws + OFF_TESQ;

    __shared__ unsigned hist[4096];
    __shared__ unsigned wsum[16], woff[16];
    __shared__ unsigned wmn[16], wmx[16];
    __shared__ unsigned sh_ulo, sh_uhi;
    __shared__ unsigned sh_bin; __shared__ int sh_rem;
    __shared__ int cnt;
    __shared__ unsigned cand_u[CAP];
    __shared__ int      cand_i[CAP];
    __shared__ float fred[16];

    // preamble: global key range from wave slots
    {
        const unsigned* rg = (const unsigned*)(ws + OFF_RANGE);
        unsigned mn = 0xFFFFFFFFu, mx = 0u;
        for (int i = t; i < NSLOT; i += 1024) {
            mn = min(mn, rg[2 * i]);
            mx = max(mx, rg[2 * i + 1]);
        }
        #pragma unroll
        for (int off = 32; off > 0; off >>= 1) {
            mn = min(mn, (unsigned)__shfl_down((int)mn, off, 64));
            mx = max(mx, (unsigned)__shfl_down((int)mx, off, 64));
        }
        if (lane == 0) { wmn[wid] = mn; wmx[wid] = mx; }
        __syncthreads();
        if (t == 0) {
            unsigned m0 = 0xFFFFFFFFu, m1 = 0u;
            for (int w = 0; w < 16; ++w) { m0 = min(m0, wmn[w]); m1 = max(m1, wmx[w]); }
            sh_ulo = m0; sh_uhi = m1;
        }
        __syncthreads();
    }
    unsigned ubase = sh_ulo;
    unsigned ulo = sh_ulo, uhi = sh_uhi;
    int rem = *topk;
    unsigned long long width = (unsigned long long)(uhi - ulo) + 1ull;

    // pass 1: histogram over 4096 linear bins
    for (int i = t; i < 4096; i += 1024) hist[i] = 0u;
    __syncthreads();
    for (int n = t; n < N; n += 1024) {
        unsigned u = uarr[n];
        unsigned bin = (unsigned)(((unsigned long long)(u - ubase) * 4096ull) / width);
        atomicAdd(&hist[bin], 1u);
    }
    __syncthreads();
    {
        unsigned b0 = (unsigned)t * 4u;
        unsigned h0 = hist[b0], h1 = hist[b0 + 1], h2 = hist[b0 + 2], h3 = hist[b0 + 3];
        unsigned s4 = h0 + h1 + h2 + h3;
        unsigned x = s4;
        #pragma unroll
        for (int off = 1; off < 64; off <<= 1) {
            unsigned y = (unsigned)__shfl_up((int)x, off, 64);
            if (lane >= off) x += y;
        }
        if (lane == 63) wsum[wid] = x;
        __syncthreads();
        if (t == 0) {
            unsigned run = 0;
            for (int w = 0; w < 16; ++w) { woff[w] = run; run += wsum[w]; }
        }
        __syncthreads();
        unsigned cumBefore = woff[wid] + x - s4;
        unsigned remu = (unsigned)rem;
        if (cumBefore < remu && remu <= cumBefore + s4) {
            unsigned cum = cumBefore, bin = b0, r2 = 1;
            unsigned hh[4] = {h0, h1, h2, h3};
            #pragma unroll
            for (int j = 0; j < 4; ++j) {
                if (cum + hh[j] >= remu) { bin = b0 + j; r2 = remu - cum; break; }
                cum += hh[j];
            }
            sh_bin = bin; sh_rem = (int)r2;
        }
        __syncthreads();
        unsigned b = sh_bin;
        rem = sh_rem;
        ulo = ubase + (unsigned)(((unsigned long long)b * width + 4095ull) / 4096ull);
        uhi = ubase + (unsigned)((((unsigned long long)(b + 1) * width + 4095ull) / 4096ull) - 1ull);
        __syncthreads();
    }

    // final: sum recovered dots below cutoff bin; collect cutoff-bin candidates
    if (t == 0) cnt = 0;
    __syncthreads();
    float lsum = 0.f;
    for (int n = t; n < N; n += 1024) {
        unsigned u = uarr[n];
        if (u < ulo) {
            lsum += 0.5f * (tesq[n] - unmapf(u));
        } else if (u <= uhi) {
            int s = atomicAdd(&cnt, 1);
            if (s < CAP) { cand_u[s] = u; cand_i[s] = n; }
        }
    }
    __syncthreads();
    int cc = cnt < CAP ? cnt : CAP;
    for (int ci = t; ci < cc; ci += 1024) {
        unsigned ui = cand_u[ci]; int ii = cand_i[ci];
        int rank = 0;
        for (int j = 0; j < cc; ++j) {
            unsigned uj = cand_u[j];
            rank += (uj < ui || (uj == ui && cand_i[j] < ii)) ? 1 : 0;
        }
        if (rank < rem) lsum += 0.5f * (tesq[ii] - unmapf(ui));
    }
    #pragma unroll
    for (int off = 32; off > 0; off >>= 1) lsum += __shfl_down(lsum, off, 64);
    if (lane == 0) fred[wid] = lsum;
    __syncthreads();
    if (t == 0) {
        float tot = 0.f;
        for (int w = 0; w < 16; ++w) tot += fred[w];
        wsw[OFF_SUMS + c] = tot;
        __threadfence();
        unsigned done = atomicAdd((unsigned*)(wsw + OFF_CNT), 1u);
        if (done == C - 1) {
            float s = 0.f;
            for (int i = 0; i < C; ++i) s += atomicAdd(&wsw[OFF_SUMS + i], 0.0f);
            out[32768] = s / (float)((*topk) * C);
        }
    }
}

extern "C" void kernel_launch(void* const* d_in, const int* in_sizes, int n_in,
                              void* d_out, int out_size, void* d_ws, size_t ws_size,
                              hipStream_t stream) {
    (void)in_sizes; (void)n_in; (void)out_size; (void)ws_size;
    const float* concept = (const float*)d_in[0];
    const float* te      = (const float*)d_in[1];
    const float* X       = (const float*)d_in[2];
    const float* hxw     = (const float*)d_in[3];
    const float* hxb     = (const float*)d_in[4];
    const int*   topk    = (const int*)d_in[5];
    float* out = (float*)d_out;
    float* ws  = (float*)d_ws;

    kprep<<<dim3(KParts + 1), dim3(256), 0, stream>>>(concept, hxw, ws);
    kgemm<<<dim3(NBLK + 1), dim3(512), 0, stream>>>(concept, te, hxw, ws, out);
    kpred<<<dim3(B / 4), dim3(256), 0, stream>>>(X, hxb, ws, out);
    k4_select<<<dim3(C), dim3(1024), 0, stream>>>(ws, ws, out, topk);
}

// Round 15
// 508.096 us; speedup vs baseline: 3.2437x; 1.0018x over previous
//
#include <hip/hip_runtime.h>
#include <hip/hip_bf16.h>
#include <stdint.h>

#define D 1024
#define N 200000
#define C 50
#define B 4096
#define CLS 4
#define KParts 16
#define CAP 4096
#define BN 256
#define NBLK 782                    // ceil(N/BN); 782*256 = 200192
#define NSLOT (NBLK * 8)            // per-wave key-range slots
#define BLROW 260                   // padded row (u32) of B tile

typedef __attribute__((ext_vector_type(8))) short short8;
typedef __attribute__((ext_vector_type(4))) float f32x4;

// ws float offsets
static const size_t OFF_U     = 0;                          // C*N uints (keys)
static const size_t OFF_TESQ  = (size_t)C * N;              // N floats
static const size_t OFF_GPART = OFF_TESQ + N;               // KParts*2500
static const size_t OFF_WPART = OFF_GPART + KParts * 2500;  // KParts*200
static const size_t OFF_ABF   = ((OFF_WPART + KParts * 200 + 3) / 4) * 4;  // 65536 ushort
static const size_t OFF_RANGE = OFF_ABF + 32768;            // NSLOT*2 uints
static const size_t OFF_SUMS  = OFF_RANGE + 2 * NSLOT;      // C floats
static const size_t OFF_CNT   = OFF_SUMS + C;               // 1 uint
static const size_t OFF_W8    = ((OFF_CNT + 1 + 3) / 4) * 4; // D*8 floats

__device__ __forceinline__ unsigned mapf(float v) {
    unsigned u = __float_as_uint(v);
    return (u & 0x80000000u) ? ~u : (u | 0x80000000u);
}
__device__ __forceinline__ float unmapf(unsigned u) {
    unsigned b = (u & 0x80000000u) ? (u ^ 0x80000000u) : ~u;
    return __uint_as_float(b);
}
__device__ __forceinline__ unsigned keyu(float dot, float tesq) {
    return mapf(fmaf(-2.0f, dot, tesq));
}
__device__ __forceinline__ unsigned short f2bf(float f) {   // RNE fp32->bf16
    unsigned u = __float_as_uint(f);
    u += 0x7FFFu + ((u >> 16) & 1u);
    return (unsigned short)(u >> 16);
}

// raw barrier: order LDS only; keep global loads in flight across it
#define TILE_BARRIER() do {                                   \
    asm volatile("s_waitcnt lgkmcnt(0)" ::: "memory");        \
    __builtin_amdgcn_s_barrier();                             \
    asm volatile("" ::: "memory");                            \
} while (0)

// ---------------- Kprep: gram/wc partials (blocks 0..15) + A-bf16 pack (block 16) ----------
__global__ __launch_bounds__(256) void kprep(
    const float* __restrict__ concept, const float* __restrict__ hxw,
    float* __restrict__ ws)
{
    int t = threadIdx.x;

    if (blockIdx.x < KParts) {
        __shared__ __align__(16) float ct[64 * 50];
        __shared__ float hs[4 * 64];
        int bid = blockIdx.x;
        int d0 = bid * 64;

        for (int i = t; i < 64 * 50; i += 256) ct[i] = concept[d0 * 50 + i];
        {
            int j = t >> 6, dd = t & 63;
            hs[t] = hxw[j * D + d0 + dd];
        }
        __syncthreads();

        float* gp = ws + OFF_GPART + (size_t)bid * 2500;
        for (int p = t; p < 2500; p += 256) {
            int i = p / 50, j = p - i * 50;
            float acc = 0.f;
            #pragma unroll 8
            for (int dd = 0; dd < 64; ++dd)
                acc = fmaf(ct[dd * 50 + i], ct[dd * 50 + j], acc);
            gp[p] = acc;
        }
        float* wp = ws + OFF_WPART + (size_t)bid * 200;
        if (t < 200) {
            int j = t / 50, c = t - j * 50;
            float acc = 0.f;
            #pragma unroll 8
            for (int dd = 0; dd < 64; ++dd)
                acc = fmaf(hs[j * 64 + dd], ct[dd * 50 + c], acc);
            wp[t] = acc;
        }
        return;
    }

    // A-pack: ap[((ks*4+g)*64 + m)*8 + j] = bf16(concept[ks*32+g*8+j][m]), m<50 else 0
    unsigned short* ap = (unsigned short*)(ws + OFF_ABF);
    for (int idx = t; idx < 8192; idx += 256) {
        int ks = idx >> 8;
        int g  = (idx >> 6) & 3;
        int m  = idx & 63;
        unsigned short v[8];
        #pragma unroll
        for (int j = 0; j < 8; ++j) {
            int k = ks * 32 + g * 8 + j;
            v[j] = (m < 50) ? f2bf(concept[k * 50 + m]) : (unsigned short)0;
        }
        uint4 pk;
        pk.x = (unsigned)v[0] | ((unsigned)v[1] << 16);
        pk.y = (unsigned)v[2] | ((unsigned)v[3] << 16);
        pk.z = (unsigned)v[4] | ((unsigned)v[5] << 16);
        pk.w = (unsigned)v[6] | ((unsigned)v[7] << 16);
        *(uint4*)(ap + (size_t)idx * 8) = pk;
    }
}

// ---------------- Kgemm: MFMA dots+keys+tesq (blocks 0..781) | solve (block 782) ----------
__global__ __launch_bounds__(512, 4) void kgemm(
    const float* __restrict__ concept, const float* __restrict__ te,
    const float* __restrict__ hxw, float* __restrict__ ws,
    float* __restrict__ out)
{
    __shared__ __align__(16) unsigned char smem[42496];

    int t = threadIdx.x;
    int l = t & 63, w = t >> 6;

    if (blockIdx.x == NBLK) {
        // ---- solve role: gram sum, metrics, pivotless GJ on [G|wc^T], W8 ----
        float* gsh  = (float*)smem;             // 2500
        float* Asv  = (float*)(smem + 10000);   // 50*56
        float* colp = (float*)(smem + 21200);   // 50
        float* part = (float*)(smem + 21408);   // 3*8

        if (t == 0) ((unsigned*)(ws + OFF_CNT))[0] = 0u;

        float s_all = 0.f, s_tr = 0.f, s_abs = 0.f;
        for (int p = t; p < 2500; p += 512) {
            float g = 0.f;
            #pragma unroll
            for (int b = 0; b < KParts; ++b)
                g += ws[OFF_GPART + (size_t)b * 2500 + p];
            gsh[p] = g;
            int i = p / 50, jj = p - i * 50;
            float e = (i == jj) ? 1.0f : 0.0f;
            s_all += g;
            if (i == jj) s_tr += g;
            s_abs += fabsf(g - e);
        }
        #pragma unroll
        for (int off = 32; off > 0; off >>= 1) {
            s_all += __shfl_down(s_all, off, 64);
            s_tr  += __shfl_down(s_tr,  off, 64);
            s_abs += __shfl_down(s_abs, off, 64);
        }
        if (l == 0) { part[0 * 8 + w] = s_all; part[1 * 8 + w] = s_tr; part[2 * 8 + w] = s_abs; }
        __syncthreads();
        if (t == 0) {
            float a = 0.f, tr = 0.f, ab = 0.f;
            for (int i = 0; i < 8; ++i) {
                a += part[0 * 8 + i]; tr += part[1 * 8 + i]; ab += part[2 * 8 + i];
            }
            out[32769] = (a - tr) / 2500.0f;
            out[32770] = tr / 2500.0f;
            out[32771] = ab / 2500.0f;
        }

        for (int p = t; p < 50 * 56; p += 512) {
            int r = p / 56, col = p - r * 56;
            float v = 0.f;
            if (col < 50) v = gsh[r * 50 + col];
            else if (col < 54) {
                float ww = 0.f;
                #pragma unroll
                for (int b = 0; b < KParts; ++b)
                    ww += ws[OFF_WPART + (size_t)b * 200 + (col - 50) * 50 + r];
                v = ww;
            }
            Asv[p] = v;
        }
        __syncthreads();

        for (int pc = 0; pc < C; ++pc) {
            if (t < C) colp[t] = Asv[t * 56 + pc];
            __syncthreads();
            float pinv = 1.0f / colp[pc];
            if (t < 56) Asv[pc * 56 + t] *= pinv;
            __syncthreads();
            for (int p = t; p < 50 * 56; p += 512) {
                int r = p / 56, col = p - r * 56;
                if (r != pc) Asv[p] = fmaf(-colp[r], Asv[pc * 56 + col], Asv[p]);
            }
            __syncthreads();
        }

        for (int d = t; d < D; d += 512) {
            float wy0 = 0.f, wy1 = 0.f, wy2 = 0.f, wy3 = 0.f;
            for (int c = 0; c < C; ++c) {
                float cv = concept[d * 50 + c];
                wy0 = fmaf(cv, Asv[c * 56 + 50], wy0);
                wy1 = fmaf(cv, Asv[c * 56 + 51], wy1);
                wy2 = fmaf(cv, Asv[c * 56 + 52], wy2);
                wy3 = fmaf(cv, Asv[c * 56 + 53], wy3);
            }
            float4 lo, hi;
            lo.x = hxw[0 * D + d]; lo.y = hxw[1 * D + d];
            lo.z = hxw[2 * D + d]; lo.w = hxw[3 * D + d];
            hi.x = wy0; hi.y = wy1; hi.z = wy2; hi.w = wy3;
            *(float4*)(ws + OFF_W8 + (size_t)d * 8)     = lo;
            *(float4*)(ws + OFF_W8 + (size_t)d * 8 + 4) = hi;
        }
        return;
    }

    // ---- GEMM role ----
    unsigned* Blb = (unsigned*)smem;                  // [2][16*260]
    float* tsp = (float*)(smem + 33280);              // [8][256]
    float* tsf = (float*)(smem + 33280 + 8192);       // [256]

    int nbase = blockIdx.x * BN;
    int nq = t & 63, rp = w;
    int ncol0 = nbase + nq * 4;
    bool colv = (ncol0 < N);

    f32x4 accf[2][4];
    #pragma unroll
    for (int mf = 0; mf < 2; ++mf)
        #pragma unroll
        for (int nf = 0; nf < 4; ++nf)
            accf[mf][nf] = (f32x4)(0.0f);
    float ts0 = 0.f, ts1 = 0.f, ts2 = 0.f, ts3 = 0.f;

    const unsigned short* ap = (const unsigned short*)(ws + OFF_ABF);
    int g = l >> 4;
    int mhalf = w >> 2;
    int nnb = (w & 3) * 64 + (l & 15);

    auto ldtile = [&](int ks, float4* xr) {
        #pragma unroll
        for (int pi = 0; pi < 2; ++pi) {
            int pair = rp + pi * 8;
            int k0 = ks * 32 + pair * 2;
            if (colv) {
                xr[2 * pi]     = *(const float4*)(te + (size_t)k0 * N + ncol0);
                xr[2 * pi + 1] = *(const float4*)(te + (size_t)(k0 + 1) * N + ncol0);
            } else {
                xr[2 * pi]     = make_float4(0.f, 0.f, 0.f, 0.f);
                xr[2 * pi + 1] = make_float4(0.f, 0.f, 0.f, 0.f);
            }
        }
    };

    auto cvt_write = [&](int buf, float4* xr) {
        #pragma unroll
        for (int pi = 0; pi < 2; ++pi) {
            int pair = rp + pi * 8;
            float4 xa = xr[2 * pi], xb = xr[2 * pi + 1];
            union { __hip_bfloat162 h; unsigned u; } p0, p1, p2, p3;
            p0.h = __float22bfloat162_rn(make_float2(xa.x, xb.x));
            p1.h = __float22bfloat162_rn(make_float2(xa.y, xb.y));
            p2.h = __float22bfloat162_rn(make_float2(xa.z, xb.z));
            p3.h = __float22bfloat162_rn(make_float2(xa.w, xb.w));
            float fa0 = __uint_as_float(p0.u << 16), fb0 = __uint_as_float(p0.u & 0xFFFF0000u);
            float fa1 = __uint_as_float(p1.u << 16), fb1 = __uint_as_float(p1.u & 0xFFFF0000u);
            float fa2 = __uint_as_float(p2.u << 16), fb2 = __uint_as_float(p2.u & 0xFFFF0000u);
            float fa3 = __uint_as_float(p3.u << 16), fb3 = __uint_as_float(p3.u & 0xFFFF0000u);
            ts0 = fmaf(fa0, fa0, fmaf(fb0, fb0, ts0));
            ts1 = fmaf(fa1, fa1, fmaf(fb1, fb1, ts1));
            ts2 = fmaf(fa2, fa2, fmaf(fb2, fb2, ts2));
            ts3 = fmaf(fa3, fa3, fmaf(fb3, fb3, ts3));
            uint4 pk;
            pk.x = p0.u; pk.y = p1.u; pk.z = p2.u; pk.w = p3.u;
            *(uint4*)(&Blb[buf * (16 * BLROW) + pair * BLROW + nq * 4]) = pk;
        }
    };

    auto body = [&](int ks, float4* rload, float4* rcons) {
        if (ks < 30) ldtile(ks + 2, rload);     // 2-deep prefetch, stays in flight across barriers

        short8 af0 = *(const short8*)(ap + ((size_t)(ks * 4 + g) * 64 + mhalf * 32 + 0 * 16 + (l & 15)) * 8);
        short8 af1 = *(const short8*)(ap + ((size_t)(ks * 4 + g) * 64 + mhalf * 32 + 1 * 16 + (l & 15)) * 8);

        const unsigned* Bc = Blb + (ks & 1) * (16 * BLROW);
        #pragma unroll
        for (int nf = 0; nf < 4; ++nf) {
            int nn = nnb + nf * 16;
            union { unsigned u[4]; short8 s; } bu;
            bu.u[0] = Bc[(g * 4 + 0) * BLROW + nn];
            bu.u[1] = Bc[(g * 4 + 1) * BLROW + nn];
            bu.u[2] = Bc[(g * 4 + 2) * BLROW + nn];
            bu.u[3] = Bc[(g * 4 + 3) * BLROW + nn];
            accf[0][nf] = __builtin_amdgcn_mfma_f32_16x16x32_bf16(af0, bu.s, accf[0][nf], 0, 0, 0);
            accf[1][nf] = __builtin_amdgcn_mfma_f32_16x16x32_bf16(af1, bu.s, accf[1][nf], 0, 0, 0);
        }

        if (ks < 31) cvt_write((ks + 1) & 1, rcons);
    };

    float4 r0[4], r1[4];
    ldtile(0, r0);
    ldtile(1, r1);
    cvt_write(0, r0);

    #pragma unroll 1
    for (int ks = 0; ks < 32; ks += 2) {
        TILE_BARRIER();
        body(ks, r0, r1);       // loads ks+2 -> r0, consumes r1 (tile ks+1)
        TILE_BARRIER();
        body(ks + 1, r1, r0);   // loads ks+3 -> r1, consumes r0 (tile ks+2)
    }

    // tesq reduce across the 8 pair-groups
    __syncthreads();
    tsp[rp * 256 + nq * 4 + 0] = ts0;
    tsp[rp * 256 + nq * 4 + 1] = ts1;
    tsp[rp * 256 + nq * 4 + 2] = ts2;
    tsp[rp * 256 + nq * 4 + 3] = ts3;
    __syncthreads();
    if (t < 64) {
        float4 s = make_float4(0.f, 0.f, 0.f, 0.f);
        #pragma unroll
        for (int r = 0; r < 8; ++r) {
            float4 v = *(const float4*)(&tsp[r * 256 + t * 4]);
            s.x += v.x; s.y += v.y; s.z += v.z; s.w += v.w;
        }
        *(float4*)(&tsf[t * 4]) = s;
        if (nbase + t * 4 < N)
            *(float4*)(ws + OFF_TESQ + nbase + t * 4) = s;
    }
    __syncthreads();

    // epilogue: keys + per-wave range
    unsigned* uws = (unsigned*)ws;
    unsigned kmin = 0xFFFFFFFFu, kmax = 0u;
    #pragma unroll
    for (int mf = 0; mf < 2; ++mf) {
        #pragma unroll
        for (int nf = 0; nf < 4; ++nf) {
            int nloc = nnb + nf * 16;
            int nabs = nbase + nloc;
            #pragma unroll
            for (int r = 0; r < 4; ++r) {
                int c = mhalf * 32 + mf * 16 + (l >> 4) * 4 + r;   // C/D row map (m89)
                if (c < 50 && nabs < N) {
                    unsigned u = keyu(accf[mf][nf][r], tsf[nloc]);
                    uws[(size_t)c * N + nabs] = u;
                    kmin = min(kmin, u);
                    kmax = max(kmax, u);
                }
            }
        }
    }
    #pragma unroll
    for (int off = 32; off > 0; off >>= 1) {
        kmin = min(kmin, (unsigned)__shfl_down((int)kmin, off, 64));
        kmax = max(kmax, (unsigned)__shfl_down((int)kmax, off, 64));
    }
    if (l == 0) {
        int slot = blockIdx.x * 8 + w;
        ((unsigned*)(ws + OFF_RANGE))[2 * slot]     = kmin;
        ((unsigned*)(ws + OFF_RANGE))[2 * slot + 1] = kmax;
    }
}

// ---------------- Kpred: [orig_pred | y_pred] = X @ W8 + bias -----------------
__global__ __launch_bounds__(256) void kpred(
    const float* __restrict__ X, const float* __restrict__ hxb,
    const float* __restrict__ ws, float* __restrict__ out)
{
    int t = threadIdx.x;
    int lane = t & 63, w = t >> 6;
    int r = blockIdx.x * 4 + w;
    const float* xr = X + (size_t)r * D;
    const float* w8 = ws + OFF_W8;

    float acc[8];
    #pragma unroll
    for (int j = 0; j < 8; ++j) acc[j] = 0.f;
    #pragma unroll
    for (int i = 0; i < 16; ++i) {
        int d = i * 64 + lane;
        float x = xr[d];
        float4 lo = *(const float4*)(w8 + (size_t)d * 8);
        float4 hi = *(const float4*)(w8 + (size_t)d * 8 + 4);
        acc[0] = fmaf(x, lo.x, acc[0]);
        acc[1] = fmaf(x, lo.y, acc[1]);
        acc[2] = fmaf(x, lo.z, acc[2]);
        acc[3] = fmaf(x, lo.w, acc[3]);
        acc[4] = fmaf(x, hi.x, acc[4]);
        acc[5] = fmaf(x, hi.y, acc[5]);
        acc[6] = fmaf(x, hi.z, acc[6]);
        acc[7] = fmaf(x, hi.w, acc[7]);
    }
    #pragma unroll
    for (int j = 0; j < 8; ++j) {
        float v = acc[j];
        #pragma unroll
        for (int off = 32; off > 0; off >>= 1) v += __shfl_down(v, off, 64);
        if (lane == 0) {
            float b = hxb[j & 3];
            if (j < 4) out[(size_t)r * CLS + j] = v + b;
            else       out[16384 + (size_t)r * CLS + (j - 4)] = v + b;
        }
    }
}

// ---------------- K4: GR preamble + top-k from u keys + fused L_sparse_1 ------
__global__ __launch_bounds__(1024) void k4_select(
    const float* __restrict__ ws, float* __restrict__ wsw,
    float* __restrict__ out, const int* __restrict__ topk)
{
    int c = blockIdx.x, t = threadIdx.x;
    int lane = t & 63, wid = t >> 6;
    const unsigned* uarr = (const unsigned*)ws + (size_t)c * N;
    const float* tesq = ws + OFF_TESQ;

    __shared__ unsigned hist[4096];
    __shared__ unsigned wsum[16], woff[16];
    __shared__ unsigned wmn[16], wmx[16];
    __shared__ unsigned sh_ulo, sh_uhi;
    __shared__ unsigned sh_bin; __shared__ int sh_rem;
    __shared__ int cnt;
    __shared__ unsigned cand_u[CAP];
    __shared__ int      cand_i[CAP];
    __shared__ float fred[16];

    // preamble: global key range from wave slots
    {
        const unsigned* rg = (const unsigned*)(ws + OFF_RANGE);
        unsigned mn = 0xFFFFFFFFu, mx = 0u;
        for (int i = t; i < NSLOT; i += 1024) {
            mn = min(mn, rg[2 * i]);
            mx = max(mx, rg[2 * i + 1]);
        }
        #pragma unroll
        for (int off = 32; off > 0; off >>= 1) {
            mn = min(mn, (unsigned)__shfl_down((int)mn, off, 64));
            mx = max(mx, (unsigned)__shfl_down((int)mx, off, 64));
        }
        if (lane == 0) { wmn[wid] = mn; wmx[wid] = mx; }
        __syncthreads();
        if (t == 0) {
            unsigned m0 = 0xFFFFFFFFu, m1 = 0u;
            for (int w = 0; w < 16; ++w) { m0 = min(m0, wmn[w]); m1 = max(m1, wmx[w]); }
            sh_ulo = m0; sh_uhi = m1;
        }
        __syncthreads();
    }
    unsigned ubase = sh_ulo;
    unsigned ulo = sh_ulo, uhi = sh_uhi;
    int rem = *topk;
    unsigned long long width = (unsigned long long)(uhi - ulo) + 1ull;

    // pass 1: histogram over 4096 linear bins
    for (int i = t; i < 4096; i += 1024) hist[i] = 0u;
    __syncthreads();
    for (int n = t; n < N; n += 1024) {
        unsigned u = uarr[n];
        unsigned bin = (unsigned)(((unsigned long long)(u - ubase) * 4096ull) / width);
        atomicAdd(&hist[bin], 1u);
    }
    __syncthreads();
    {
        unsigned b0 = (unsigned)t * 4u;
        unsigned h0 = hist[b0], h1 = hist[b0 + 1], h2 = hist[b0 + 2], h3 = hist[b0 + 3];
        unsigned s4 = h0 + h1 + h2 + h3;
        unsigned x = s4;
        #pragma unroll
        for (int off = 1; off < 64; off <<= 1) {
            unsigned y = (unsigned)__shfl_up((int)x, off, 64);
            if (lane >= off) x += y;
        }
        if (lane == 63) wsum[wid] = x;
        __syncthreads();
        if (t == 0) {
            unsigned run = 0;
            for (int w = 0; w < 16; ++w) { woff[w] = run; run += wsum[w]; }
        }
        __syncthreads();
        unsigned cumBefore = woff[wid] + x - s4;
        unsigned remu = (unsigned)rem;
        if (cumBefore < remu && remu <= cumBefore + s4) {
            unsigned cum = cumBefore, bin = b0, r2 = 1;
            unsigned hh[4] = {h0, h1, h2, h3};
            #pragma unroll
            for (int j = 0; j < 4; ++j) {
                if (cum + hh[j] >= remu) { bin = b0 + j; r2 = remu - cum; break; }
                cum += hh[j];
            }
            sh_bin = bin; sh_rem = (int)r2;
        }
        __syncthreads();
        unsigned b = sh_bin;
        rem = sh_rem;
        ulo = ubase + (unsigned)(((unsigned long long)b * width + 4095ull) / 4096ull);
        uhi = ubase + (unsigned)((((unsigned long long)(b + 1) * width + 4095ull) / 4096ull) - 1ull);
        __syncthreads();
    }

    // final: sum recovered dots below cutoff bin; collect cutoff-bin candidates
    if (t == 0) cnt = 0;
    __syncthreads();
    float lsum = 0.f;
    for (int n = t; n < N; n += 1024) {
        unsigned u = uarr[n];
        if (u < ulo) {
            lsum += 0.5f * (tesq[n] - unmapf(u));
        } else if (u <= uhi) {
            int s = atomicAdd(&cnt, 1);
            if (s < CAP) { cand_u[s] = u; cand_i[s] = n; }
        }
    }
    __syncthreads();
    int cc = cnt < CAP ? cnt : CAP;
    for (int ci = t; ci < cc; ci += 1024) {
        unsigned ui = cand_u[ci]; int ii = cand_i[ci];
        int rank = 0;
        for (int j = 0; j < cc; ++j) {
            unsigned uj = cand_u[j];
            rank += (uj < ui || (uj == ui && cand_i[j] < ii)) ? 1 : 0;
        }
        if (rank < rem) lsum += 0.5f * (tesq[ii] - unmapf(ui));
    }
    #pragma unroll
    for (int off = 32; off > 0; off >>= 1) lsum += __shfl_down(lsum, off, 64);
    if (lane == 0) fred[wid] = lsum;
    __syncthreads();
    if (t == 0) {
        float tot = 0.f;
        for (int w = 0; w < 16; ++w) tot += fred[w];
        wsw[OFF_SUMS + c] = tot;
        __threadfence();
        unsigned done = atomicAdd((unsigned*)(wsw + OFF_CNT), 1u);
        if (done == C - 1) {
            float s = 0.f;
            for (int i = 0; i < C; ++i) s += atomicAdd(&wsw[OFF_SUMS + i], 0.0f);
            out[32768] = s / (float)((*topk) * C);
        }
    }
}

extern "C" void kernel_launch(void* const* d_in, const int* in_sizes, int n_in,
                              void* d_out, int out_size, void* d_ws, size_t ws_size,
                              hipStream_t stream) {
    (void)in_sizes; (void)n_in; (void)out_size; (void)ws_size;
    const float* concept = (const float*)d_in[0];
    const float* te      = (const float*)d_in[1];
    const float* X       = (const float*)d_in[2];
    const float* hxw     = (const float*)d_in[3];
    const float* hxb     = (const float*)d_in[4];
    const int*   topk    = (const int*)d_in[5];
    float* out = (float*)d_out;
    float* ws  = (float*)d_ws;

    kprep<<<dim3(KParts + 1), dim3(256), 0, stream>>>(concept, hxw, ws);
    kgemm<<<dim3(NBLK + 1), dim3(512), 0, stream>>>(concept, te, hxw, ws, out);
    kpred<<<dim3(B / 4), dim3(256), 0, stream>>>(X, hxb, ws, out);
    k4_select<<<dim3(C), dim3(1024), 0, stream>>>(ws, ws, out, topk);
}